// Round 1
// baseline (1769.881 us; speedup 1.0000x reference)
//
#include <hip/hip_runtime.h>
#include <stdint.h>

#define N_NODES   100000
#define N_EDGES   800000
#define NODE_DIM  128
#define HIDDEN    256
#define OUT_DIM   512
#define N_LAYERS  4
#define N_GRAPHS  64

typedef _Float16 f16;
typedef __attribute__((ext_vector_type(8))) _Float16 f16x8;
typedef __attribute__((ext_vector_type(4))) _Float16 f16x4;
typedef __attribute__((ext_vector_type(4))) float    f32x4;

// ---------------- fp32 -> fp16 conversion (vectorized) ----------------
__global__ void k_f2h(const float* __restrict__ in, f16* __restrict__ out, int n4) {
    int i = blockIdx.x * 256 + threadIdx.x;
    if (i < n4) {
        f32x4 v = *(const f32x4*)(in + (size_t)i * 4);
        f16x4 o;
        o[0] = (f16)v[0]; o[1] = (f16)v[1]; o[2] = (f16)v[2]; o[3] = (f16)v[3];
        *(f16x4*)(out + (size_t)i * 4) = o;
    }
}

// ---------------- CSR build: histogram over dst ----------------
__global__ void k_hist(const int* __restrict__ ei, int* __restrict__ deg) {
    int e = blockIdx.x * 256 + threadIdx.x;
    if (e < N_EDGES) atomicAdd(&deg[ei[N_EDGES + e]], 1);
}

// ---------------- CSR build: exclusive scan (single block) ----------------
__global__ __launch_bounds__(1024) void k_scan(const int* __restrict__ deg,
                                               int* __restrict__ rowptr,
                                               int* __restrict__ cursor) {
    __shared__ int ssum[1024];
    const int tid = threadIdx.x;
    const int C = (N_NODES + 1023) / 1024;     // 98
    int lo = tid * C, hi = lo + C;
    if (hi > N_NODES) hi = N_NODES;
    int s = 0;
    for (int i = lo; i < hi; ++i) s += deg[i];
    ssum[tid] = s;
    __syncthreads();
    // Hillis-Steele inclusive scan over 1024 partials
    for (int off = 1; off < 1024; off <<= 1) {
        int v = (tid >= off) ? ssum[tid - off] : 0;
        __syncthreads();
        ssum[tid] += v;
        __syncthreads();
    }
    int run = (tid > 0) ? ssum[tid - 1] : 0;   // exclusive prefix
    for (int i = lo; i < hi; ++i) {
        rowptr[i] = run; cursor[i] = run;
        run += deg[i];
    }
    if (tid == 1023) rowptr[N_NODES] = ssum[1023];
}

// ---------------- CSR build: scatter src into col ----------------
__global__ void k_scatter(const int* __restrict__ ei, int* __restrict__ cursor,
                          int* __restrict__ col) {
    int e = blockIdx.x * 256 + threadIdx.x;
    if (e < N_EDGES) {
        int d = ei[N_EDGES + e];
        int p = atomicAdd(&cursor[d], 1);
        col[p] = ei[e];
    }
}

// ---------------- aggregation: z = (1+eps)*h + sum_{s in N(v)} h[s], fp16 out ----------------
__global__ __launch_bounds__(256) void k_agg(const f16* __restrict__ h,
                                             const int* __restrict__ rowptr,
                                             const int* __restrict__ col,
                                             const float* __restrict__ eps, int layer,
                                             f16* __restrict__ z) {
    int node = blockIdx.x * 4 + (threadIdx.x >> 6);
    if (node >= N_NODES) return;
    int lane = threadIdx.x & 63;
    int c0 = lane * 4;                         // 64 lanes x 4 ch = 256
    float e1 = 1.0f + eps[layer];
    f16x4 hv = *(const f16x4*)(h + (size_t)node * HIDDEN + c0);
    float a0 = e1 * (float)hv[0], a1 = e1 * (float)hv[1];
    float a2 = e1 * (float)hv[2], a3 = e1 * (float)hv[3];
    int jb = rowptr[node], je = rowptr[node + 1];
    for (int j = jb; j < je; ++j) {
        int s = col[j];
        f16x4 v = *(const f16x4*)(h + (size_t)s * HIDDEN + c0);
        a0 += (float)v[0]; a1 += (float)v[1]; a2 += (float)v[2]; a3 += (float)v[3];
    }
    f16x4 o;
    o[0] = (f16)a0; o[1] = (f16)a1; o[2] = (f16)a2; o[3] = (f16)a3;
    *(f16x4*)(z + (size_t)node * HIDDEN + c0) = o;
}

// ---------------- GEMM: C[M][256] = relu(A[M][K] @ B[256][K]^T + bias), f16 in/out ----------------
// 128x128 tile, 4 waves (2x2), mfma_f32_16x16x32_f16, global_load_lds staging,
// T2 XOR-swizzle done via pre-swizzled GLOBAL source + swizzled ds_read (rule #21).
__global__ __launch_bounds__(256) void k_gemm(const f16* __restrict__ A,
                                              const f16* __restrict__ B,
                                              const float* __restrict__ bias,
                                              f16* __restrict__ C, int M, int K) {
    __shared__ f16 As[128 * 64];   // [row][64] fp16, 16 KB (stored source-swizzled)
    __shared__ f16 Bs[128 * 64];
    const int bm = blockIdx.x, bn = blockIdx.y;
    const int tid = threadIdx.x, wid = tid >> 6, lane = tid & 63;
    const int wr = wid >> 1, wc = wid & 1;     // 2x2 wave grid, each wave 64x64
    const int row0 = bm * 128, col0 = bn * 128;
    f32x4 acc[4][4] = {};

    for (int k0 = 0; k0 < K; k0 += 64) {
#pragma unroll
        for (int r = 0; r < 4; ++r) {
            int chunk = lane + (wid << 6) + (r << 8);    // 0..1023 16B chunks
            int arow = chunk >> 3;                        // 8 chunks per 128B row
            int c8   = chunk & 7;
            int sc8  = c8 ^ (arow & 7);                   // inverse-swizzled source col
            int gar  = row0 + arow; if (gar >= M) gar = M - 1;   // tail clamp (rows >= M discarded)
            const f16* srcA = A + (size_t)gar * K + k0 + sc8 * 8;
            const f16* srcB = B + (size_t)(col0 + arow) * K + k0 + sc8 * 8;
            f16* ldsbA = As + ((size_t)((wid << 6) + (r << 8))) * 8;  // wave-uniform base, lane*16 implicit
            f16* ldsbB = Bs + ((size_t)((wid << 6) + (r << 8))) * 8;
            __builtin_amdgcn_global_load_lds((const __attribute__((address_space(1))) void*)srcA,
                                             (__attribute__((address_space(3))) void*)ldsbA, 16, 0, 0);
            __builtin_amdgcn_global_load_lds((const __attribute__((address_space(1))) void*)srcB,
                                             (__attribute__((address_space(3))) void*)ldsbB, 16, 0, 0);
        }
        __syncthreads();
#pragma unroll
        for (int ks = 0; ks < 2; ++ks) {
            f16x8 af[4], bf[4];
            const int klo = (lane >> 4);                  // k-group 0..3
#pragma unroll
            for (int m = 0; m < 4; ++m) {
                int ra = wr * 64 + m * 16 + (lane & 15);
                af[m] = *(const f16x8*)(As + ra * 64 + ((((ks << 2) | klo) ^ (ra & 7)) << 3));
            }
#pragma unroll
            for (int n = 0; n < 4; ++n) {
                int rb = wc * 64 + n * 16 + (lane & 15);
                bf[n] = *(const f16x8*)(Bs + rb * 64 + ((((ks << 2) | klo) ^ (rb & 7)) << 3));
            }
#pragma unroll
            for (int m = 0; m < 4; ++m)
#pragma unroll
                for (int n = 0; n < 4; ++n)
                    acc[m][n] = __builtin_amdgcn_mfma_f32_16x16x32_f16(af[m], bf[n], acc[m][n], 0, 0, 0);
        }
        __syncthreads();
    }
    // epilogue: bias + relu + fp16 store. D: col=lane&15, row=(lane>>4)*4+j
#pragma unroll
    for (int n = 0; n < 4; ++n) {
        int gc = col0 + wc * 64 + n * 16 + (lane & 15);
        float bv = bias[gc];
#pragma unroll
        for (int m = 0; m < 4; ++m) {
            int gr0 = row0 + wr * 64 + m * 16 + ((lane >> 4) << 2);
#pragma unroll
            for (int j = 0; j < 4; ++j) {
                int gr = gr0 + j;
                if (gr < M) {
                    float v = acc[m][n][j] + bv;
                    v = fmaxf(v, 0.0f);
                    C[(size_t)gr * HIDDEN + gc] = (f16)v;
                }
            }
        }
    }
}

// ---------------- graph-count histogram ----------------
__global__ void k_count(const int* __restrict__ batch, int* __restrict__ counts) {
    int i = blockIdx.x * 256 + threadIdx.x;
    if (i < N_NODES) atomicAdd(&counts[batch[i]], 1);
}

// ---------------- pooled sums (batch is sorted) ----------------
__global__ __launch_bounds__(256) void k_pool(const f16* __restrict__ h,
                                              const int* __restrict__ batch,
                                              float* __restrict__ sums) {
    int c = threadIdx.x;                       // channel 0..255
    int n0 = blockIdx.x * 256;
    int nend = n0 + 256; if (nend > N_NODES) nend = N_NODES;
    float acc = 0.0f;
    int cur = batch[n0];
    for (int n = n0; n < nend; ++n) {
        int g = batch[n];
        if (g != cur) {
            atomicAdd(&sums[(size_t)cur * HIDDEN + c], acc);
            acc = 0.0f; cur = g;
        }
        acc += (float)h[(size_t)n * HIDDEN + c];
    }
    atomicAdd(&sums[(size_t)cur * HIDDEN + c], acc);
}

// ---------------- head MLP (fp32, tiny) ----------------
__global__ __launch_bounds__(256) void k_head(const float* __restrict__ sums,
                                              const int* __restrict__ counts,
                                              const float* __restrict__ w1,
                                              const float* __restrict__ b1,
                                              const float* __restrict__ w2,
                                              const float* __restrict__ b2,
                                              float* __restrict__ out) {
    __shared__ float hg[HIDDEN];
    __shared__ float t[HIDDEN];
    int g = blockIdx.x, tid = threadIdx.x;
    float cnt = (float)(counts[g] > 1 ? counts[g] : 1);
    hg[tid] = sums[(size_t)g * HIDDEN + tid] / cnt;
    __syncthreads();
    float a = b1[tid];
    for (int k = 0; k < HIDDEN; ++k) a += hg[k] * w1[(size_t)tid * HIDDEN + k];
    t[tid] = fmaxf(a, 0.0f);
    __syncthreads();
    for (int j = tid; j < OUT_DIM; j += 256) {
        float o = b2[j];
        for (int k = 0; k < HIDDEN; ++k) o += t[k] * w2[(size_t)j * HIDDEN + k];
        out[(size_t)g * OUT_DIM + j] = o;
    }
}

extern "C" void kernel_launch(void* const* d_in, const int* in_sizes, int n_in,
                              void* d_out, int out_size, void* d_ws, size_t ws_size,
                              hipStream_t stream) {
    const float* x      = (const float*)d_in[0];
    const int*   ei     = (const int*)d_in[1];
    const int*   batch  = (const int*)d_in[2];
    const float* node_w = (const float*)d_in[3];
    const float* node_b = (const float*)d_in[4];
    const float* gw1    = (const float*)d_in[5];
    const float* gb1    = (const float*)d_in[6];
    const float* gw2    = (const float*)d_in[7];
    const float* gb2    = (const float*)d_in[8];
    const float* eps    = (const float*)d_in[9];
    const float* ow1    = (const float*)d_in[10];
    const float* ob1    = (const float*)d_in[11];
    const float* ow2    = (const float*)d_in[12];
    const float* ob2    = (const float*)d_in[13];
    float* out = (float*)d_out;

    // ---- workspace layout ----
    char* p = (char*)d_ws;
    auto alloc = [&](size_t bytes) {
        char* r = p;
        p += (bytes + 255) & ~(size_t)255;
        return (void*)r;
    };
    f16* hb   = (f16*)alloc((size_t)N_NODES * HIDDEN * 2);
    f16* zb   = (f16*)alloc((size_t)N_NODES * HIDDEN * 2);
    f16* tb   = (f16*)alloc((size_t)N_NODES * HIDDEN * 2);
    f16* xb   = (f16*)alloc((size_t)N_NODES * NODE_DIM * 2);
    f16* nwb  = (f16*)alloc((size_t)HIDDEN * NODE_DIM * 2);
    f16* w1b  = (f16*)alloc((size_t)N_LAYERS * HIDDEN * HIDDEN * 2);
    f16* w2b  = (f16*)alloc((size_t)N_LAYERS * HIDDEN * HIDDEN * 2);
    int* deg    = (int*)alloc((size_t)N_NODES * 4);
    int* rowptr = (int*)alloc((size_t)(N_NODES + 1) * 4);
    int* cursor = (int*)alloc((size_t)N_NODES * 4);
    int* col    = (int*)alloc((size_t)N_EDGES * 4);
    float* sums = (float*)alloc((size_t)N_GRAPHS * HIDDEN * 4);
    int* counts = (int*)alloc((size_t)N_GRAPHS * 4);
    (void)in_sizes; (void)n_in; (void)out_size; (void)ws_size;

    // ---- zero what we accumulate into ----
    hipMemsetAsync(deg, 0, (size_t)N_NODES * 4, stream);
    hipMemsetAsync(sums, 0, (size_t)N_GRAPHS * HIDDEN * 4, stream);
    hipMemsetAsync(counts, 0, (size_t)N_GRAPHS * 4, stream);

    // ---- fp16 conversions ----
    k_f2h<<<(N_NODES * NODE_DIM / 4 + 255) / 256, 256, 0, stream>>>(x, xb, N_NODES * NODE_DIM / 4);
    k_f2h<<<(HIDDEN * NODE_DIM / 4 + 255) / 256, 256, 0, stream>>>(node_w, nwb, HIDDEN * NODE_DIM / 4);
    k_f2h<<<(N_LAYERS * HIDDEN * HIDDEN / 4 + 255) / 256, 256, 0, stream>>>(gw1, w1b, N_LAYERS * HIDDEN * HIDDEN / 4);
    k_f2h<<<(N_LAYERS * HIDDEN * HIDDEN / 4 + 255) / 256, 256, 0, stream>>>(gw2, w2b, N_LAYERS * HIDDEN * HIDDEN / 4);

    // ---- CSR build ----
    k_hist<<<(N_EDGES + 255) / 256, 256, 0, stream>>>(ei, deg);
    k_scan<<<1, 1024, 0, stream>>>(deg, rowptr, cursor);
    k_scatter<<<(N_EDGES + 255) / 256, 256, 0, stream>>>(ei, cursor, col);

    // ---- node projection ----
    dim3 ggrid((N_NODES + 127) / 128, HIDDEN / 128);
    k_gemm<<<ggrid, 256, 0, stream>>>(xb, nwb, node_b, hb, N_NODES, NODE_DIM);

    // ---- GIN layers ----
    for (int l = 0; l < N_LAYERS; ++l) {
        k_agg<<<(N_NODES + 3) / 4, 256, 0, stream>>>(hb, rowptr, col, eps, l, zb);
        k_gemm<<<ggrid, 256, 0, stream>>>(zb, w1b + (size_t)l * HIDDEN * HIDDEN, gb1 + (size_t)l * HIDDEN,
                                          tb, N_NODES, HIDDEN);
        k_gemm<<<ggrid, 256, 0, stream>>>(tb, w2b + (size_t)l * HIDDEN * HIDDEN, gb2 + (size_t)l * HIDDEN,
                                          hb, N_NODES, HIDDEN);
    }

    // ---- pooling + head ----
    k_count<<<(N_NODES + 255) / 256, 256, 0, stream>>>(batch, counts);
    k_pool<<<(N_NODES + 255) / 256, 256, 0, stream>>>(hb, batch, sums);
    k_head<<<N_GRAPHS, 256, 0, stream>>>(sums, counts, ow1, ob1, ow2, ob2, out);
}

// Round 3
// 1233.962 us; speedup vs baseline: 1.4343x; 1.4343x over previous
//
#include <hip/hip_runtime.h>
#include <stdint.h>

#define N_NODES   100000
#define N_EDGES   800000
#define NODE_DIM  128
#define HIDDEN    256
#define OUT_DIM   512
#define N_LAYERS  4
#define N_GRAPHS  64
#define POOL_CHUNKS 8

typedef _Float16 f16;
typedef __attribute__((ext_vector_type(8))) _Float16 f16x8;
typedef __attribute__((ext_vector_type(4))) _Float16 f16x4;
typedef __attribute__((ext_vector_type(4))) float    f32x4;

// ---------------- fp32 -> fp16 conversion (vectorized) ----------------
__global__ void k_f2h(const float* __restrict__ in, f16* __restrict__ out, int n4) {
    int i = blockIdx.x * 256 + threadIdx.x;
    if (i < n4) {
        f32x4 v = *(const f32x4*)(in + (size_t)i * 4);
        f16x4 o;
        o[0] = (f16)v[0]; o[1] = (f16)v[1]; o[2] = (f16)v[2]; o[3] = (f16)v[3];
        *(f16x4*)(out + (size_t)i * 4) = o;
    }
}

// ---------------- CSR build: histogram over dst ----------------
__global__ void k_hist(const int* __restrict__ ei, int* __restrict__ deg) {
    int e = blockIdx.x * 256 + threadIdx.x;
    if (e < N_EDGES) atomicAdd(&deg[ei[N_EDGES + e]], 1);
}

// ---------------- CSR build: exclusive scan (single block) ----------------
__global__ __launch_bounds__(1024) void k_scan(const int* __restrict__ deg,
                                               int* __restrict__ rowptr,
                                               int* __restrict__ cursor) {
    __shared__ int ssum[1024];
    const int tid = threadIdx.x;
    const int C = (N_NODES + 1023) / 1024;     // 98
    int lo = tid * C, hi = lo + C;
    if (hi > N_NODES) hi = N_NODES;
    int s = 0;
    for (int i = lo; i < hi; ++i) s += deg[i];
    ssum[tid] = s;
    __syncthreads();
    // Hillis-Steele inclusive scan over 1024 partials
    for (int off = 1; off < 1024; off <<= 1) {
        int v = (tid >= off) ? ssum[tid - off] : 0;
        __syncthreads();
        ssum[tid] += v;
        __syncthreads();
    }
    int run = (tid > 0) ? ssum[tid - 1] : 0;   // exclusive prefix
    for (int i = lo; i < hi; ++i) {
        rowptr[i] = run; cursor[i] = run;
        run += deg[i];
    }
    if (tid == 1023) rowptr[N_NODES] = ssum[1023];
}

// ---------------- CSR build: scatter src into col ----------------
__global__ void k_scatter(const int* __restrict__ ei, int* __restrict__ cursor,
                          int* __restrict__ col) {
    int e = blockIdx.x * 256 + threadIdx.x;
    if (e < N_EDGES) {
        int d = ei[N_EDGES + e];
        int p = atomicAdd(&cursor[d], 1);
        col[p] = ei[e];
    }
}

// ---------------- aggregation: z = (1+eps)*h + sum_{s in N(v)} h[s], fp16 out ----------------
__global__ __launch_bounds__(256) void k_agg(const f16* __restrict__ h,
                                             const int* __restrict__ rowptr,
                                             const int* __restrict__ col,
                                             const float* __restrict__ eps, int layer,
                                             f16* __restrict__ z) {
    int node = blockIdx.x * 4 + (threadIdx.x >> 6);
    if (node >= N_NODES) return;
    int lane = threadIdx.x & 63;
    int c0 = lane * 4;                         // 64 lanes x 4 ch = 256
    float e1 = 1.0f + eps[layer];
    f16x4 hv = *(const f16x4*)(h + (size_t)node * HIDDEN + c0);
    float a0 = e1 * (float)hv[0], a1 = e1 * (float)hv[1];
    float a2 = e1 * (float)hv[2], a3 = e1 * (float)hv[3];
    int jb = rowptr[node], je = rowptr[node + 1];
    for (int j = jb; j < je; ++j) {
        int s = col[j];
        f16x4 v = *(const f16x4*)(h + (size_t)s * HIDDEN + c0);
        a0 += (float)v[0]; a1 += (float)v[1]; a2 += (float)v[2]; a3 += (float)v[3];
    }
    f16x4 o;
    o[0] = (f16)a0; o[1] = (f16)a1; o[2] = (f16)a2; o[3] = (f16)a3;
    *(f16x4*)(z + (size_t)node * HIDDEN + c0) = o;
}

// ---------------- GEMM: C[M][256] = relu(A[M][K] @ B[256][K]^T + bias), f16 in/out ----------------
// 128x128 tile, 4 waves (2x2), mfma_f32_16x16x32_f16, global_load_lds staging,
// T2 XOR-swizzle done via pre-swizzled GLOBAL source + swizzled ds_read (rule #21).
__global__ __launch_bounds__(256) void k_gemm(const f16* __restrict__ A,
                                              const f16* __restrict__ B,
                                              const float* __restrict__ bias,
                                              f16* __restrict__ C, int M, int K) {
    __shared__ f16 As[128 * 64];   // [row][64] fp16, 16 KB (stored source-swizzled)
    __shared__ f16 Bs[128 * 64];
    const int bm = blockIdx.x, bn = blockIdx.y;
    const int tid = threadIdx.x, wid = tid >> 6, lane = tid & 63;
    const int wr = wid >> 1, wc = wid & 1;     // 2x2 wave grid, each wave 64x64
    const int row0 = bm * 128, col0 = bn * 128;
    f32x4 acc[4][4] = {};

    for (int k0 = 0; k0 < K; k0 += 64) {
#pragma unroll
        for (int r = 0; r < 4; ++r) {
            int chunk = lane + (wid << 6) + (r << 8);    // 0..1023 16B chunks
            int arow = chunk >> 3;                        // 8 chunks per 128B row
            int c8   = chunk & 7;
            int sc8  = c8 ^ (arow & 7);                   // inverse-swizzled source col
            int gar  = row0 + arow; if (gar >= M) gar = M - 1;   // tail clamp (rows >= M discarded)
            const f16* srcA = A + (size_t)gar * K + k0 + sc8 * 8;
            const f16* srcB = B + (size_t)(col0 + arow) * K + k0 + sc8 * 8;
            f16* ldsbA = As + ((size_t)((wid << 6) + (r << 8))) * 8;  // wave-uniform base, lane*16 implicit
            f16* ldsbB = Bs + ((size_t)((wid << 6) + (r << 8))) * 8;
            __builtin_amdgcn_global_load_lds((const __attribute__((address_space(1))) void*)srcA,
                                             (__attribute__((address_space(3))) void*)ldsbA, 16, 0, 0);
            __builtin_amdgcn_global_load_lds((const __attribute__((address_space(1))) void*)srcB,
                                             (__attribute__((address_space(3))) void*)ldsbB, 16, 0, 0);
        }
        __syncthreads();
#pragma unroll
        for (int ks = 0; ks < 2; ++ks) {
            f16x8 af[4], bf[4];
            const int klo = (lane >> 4);                  // k-group 0..3
#pragma unroll
            for (int m = 0; m < 4; ++m) {
                int ra = wr * 64 + m * 16 + (lane & 15);
                af[m] = *(const f16x8*)(As + ra * 64 + ((((ks << 2) | klo) ^ (ra & 7)) << 3));
            }
#pragma unroll
            for (int n = 0; n < 4; ++n) {
                int rb = wc * 64 + n * 16 + (lane & 15);
                bf[n] = *(const f16x8*)(Bs + rb * 64 + ((((ks << 2) | klo) ^ (rb & 7)) << 3));
            }
#pragma unroll
            for (int m = 0; m < 4; ++m)
#pragma unroll
                for (int n = 0; n < 4; ++n)
                    acc[m][n] = __builtin_amdgcn_mfma_f32_16x16x32_f16(af[m], bf[n], acc[m][n], 0, 0, 0);
        }
        __syncthreads();
    }
    // epilogue: bias + relu + fp16 store. D: col=lane&15, row=(lane>>4)*4+j
#pragma unroll
    for (int n = 0; n < 4; ++n) {
        int gc = col0 + wc * 64 + n * 16 + (lane & 15);
        float bv = bias[gc];
#pragma unroll
        for (int m = 0; m < 4; ++m) {
            int gr0 = row0 + wr * 64 + m * 16 + ((lane >> 4) << 2);
#pragma unroll
            for (int j = 0; j < 4; ++j) {
                int gr = gr0 + j;
                if (gr < M) {
                    float v = acc[m][n][j] + bv;
                    v = fmaxf(v, 0.0f);
                    C[(size_t)gr * HIDDEN + gc] = (f16)v;
                }
            }
        }
    }
}

// ---------------- segment starts from sorted batch (atomic-free) ----------------
// starts[g] = first node index with batch >= g; starts[N_GRAPHS] = N_NODES.
__global__ void k_bounds(const int* __restrict__ batch, int* __restrict__ starts) {
    int i = blockIdx.x * 256 + threadIdx.x;
    if (i >= N_NODES) return;
    int g  = batch[i];
    int gp = (i == 0) ? -1 : batch[i - 1];
    for (int q = gp + 1; q <= g; ++q) starts[q] = i;
    if (i == N_NODES - 1) {
        for (int q = g + 1; q <= N_GRAPHS; ++q) starts[q] = N_NODES;
    }
}

// ---------------- pooled partial sums (atomic-free; batch sorted & contiguous) ----------------
__global__ __launch_bounds__(256) void k_pool(const f16* __restrict__ h,
                                              const int* __restrict__ starts,
                                              float* __restrict__ part) {
    int g = blockIdx.x, ch = blockIdx.y, c = threadIdx.x;
    int s = starts[g], e = starts[g + 1];
    int len = e - s;
    int per = (len + POOL_CHUNKS - 1) / POOL_CHUNKS;
    int lo = s + ch * per;
    int hi = lo + per; if (hi > e) hi = e;
    float acc = 0.0f;
    for (int n = lo; n < hi; ++n) acc += (float)h[(size_t)n * HIDDEN + c];
    part[((size_t)g * POOL_CHUNKS + ch) * HIDDEN + c] = acc;
}

// ---------------- head MLP (fp32, tiny) ----------------
__global__ __launch_bounds__(256) void k_head(const float* __restrict__ part,
                                              const int* __restrict__ starts,
                                              const float* __restrict__ w1,
                                              const float* __restrict__ b1,
                                              const float* __restrict__ w2,
                                              const float* __restrict__ b2,
                                              float* __restrict__ out) {
    __shared__ float hg[HIDDEN];
    __shared__ float t[HIDDEN];
    int g = blockIdx.x, tid = threadIdx.x;
    int cnti = starts[g + 1] - starts[g];
    float cnt = (float)(cnti > 1 ? cnti : 1);
    float s = 0.0f;
#pragma unroll
    for (int ch = 0; ch < POOL_CHUNKS; ++ch)
        s += part[((size_t)g * POOL_CHUNKS + ch) * HIDDEN + tid];
    hg[tid] = s / cnt;
    __syncthreads();
    float a = b1[tid];
    for (int k = 0; k < HIDDEN; ++k) a += hg[k] * w1[(size_t)tid * HIDDEN + k];
    t[tid] = fmaxf(a, 0.0f);
    __syncthreads();
    for (int j = tid; j < OUT_DIM; j += 256) {
        float o = b2[j];
        for (int k = 0; k < HIDDEN; ++k) o += t[k] * w2[(size_t)j * HIDDEN + k];
        out[(size_t)g * OUT_DIM + j] = o;
    }
}

extern "C" void kernel_launch(void* const* d_in, const int* in_sizes, int n_in,
                              void* d_out, int out_size, void* d_ws, size_t ws_size,
                              hipStream_t stream) {
    const float* x      = (const float*)d_in[0];
    const int*   ei     = (const int*)d_in[1];
    const int*   batch  = (const int*)d_in[2];
    const float* node_w = (const float*)d_in[3];
    const float* node_b = (const float*)d_in[4];
    const float* gw1    = (const float*)d_in[5];
    const float* gb1    = (const float*)d_in[6];
    const float* gw2    = (const float*)d_in[7];
    const float* gb2    = (const float*)d_in[8];
    const float* eps    = (const float*)d_in[9];
    const float* ow1    = (const float*)d_in[10];
    const float* ob1    = (const float*)d_in[11];
    const float* ow2    = (const float*)d_in[12];
    const float* ob2    = (const float*)d_in[13];
    float* out = (float*)d_out;

    // ---- workspace layout ----
    char* p = (char*)d_ws;
    auto alloc = [&](size_t bytes) {
        char* r = p;
        p += (bytes + 255) & ~(size_t)255;
        return (void*)r;
    };
    f16* hb   = (f16*)alloc((size_t)N_NODES * HIDDEN * 2);
    f16* zb   = (f16*)alloc((size_t)N_NODES * HIDDEN * 2);
    f16* tb   = (f16*)alloc((size_t)N_NODES * HIDDEN * 2);
    f16* xb   = (f16*)alloc((size_t)N_NODES * NODE_DIM * 2);
    f16* nwb  = (f16*)alloc((size_t)HIDDEN * NODE_DIM * 2);
    f16* w1b  = (f16*)alloc((size_t)N_LAYERS * HIDDEN * HIDDEN * 2);
    f16* w2b  = (f16*)alloc((size_t)N_LAYERS * HIDDEN * HIDDEN * 2);
    int* deg    = (int*)alloc((size_t)N_NODES * 4);
    int* rowptr = (int*)alloc((size_t)(N_NODES + 1) * 4);
    int* cursor = (int*)alloc((size_t)N_NODES * 4);
    int* col    = (int*)alloc((size_t)N_EDGES * 4);
    float* part = (float*)alloc((size_t)N_GRAPHS * POOL_CHUNKS * HIDDEN * 4);
    int* starts = (int*)alloc((size_t)(N_GRAPHS + 1) * 4);
    (void)in_sizes; (void)n_in; (void)out_size; (void)ws_size;

    // ---- zero what we accumulate into ----
    hipMemsetAsync(deg, 0, (size_t)N_NODES * 4, stream);

    // ---- fp16 conversions ----
    k_f2h<<<(N_NODES * NODE_DIM / 4 + 255) / 256, 256, 0, stream>>>(x, xb, N_NODES * NODE_DIM / 4);
    k_f2h<<<(HIDDEN * NODE_DIM / 4 + 255) / 256, 256, 0, stream>>>(node_w, nwb, HIDDEN * NODE_DIM / 4);
    k_f2h<<<(N_LAYERS * HIDDEN * HIDDEN / 4 + 255) / 256, 256, 0, stream>>>(gw1, w1b, N_LAYERS * HIDDEN * HIDDEN / 4);
    k_f2h<<<(N_LAYERS * HIDDEN * HIDDEN / 4 + 255) / 256, 256, 0, stream>>>(gw2, w2b, N_LAYERS * HIDDEN * HIDDEN / 4);

    // ---- CSR build ----
    k_hist<<<(N_EDGES + 255) / 256, 256, 0, stream>>>(ei, deg);
    k_scan<<<1, 1024, 0, stream>>>(deg, rowptr, cursor);
    k_scatter<<<(N_EDGES + 255) / 256, 256, 0, stream>>>(ei, cursor, col);

    // ---- segment bounds (replaces 500us atomic histogram) ----
    k_bounds<<<(N_NODES + 255) / 256, 256, 0, stream>>>(batch, starts);

    // ---- node projection ----
    dim3 ggrid((N_NODES + 127) / 128, HIDDEN / 128);
    k_gemm<<<ggrid, 256, 0, stream>>>(xb, nwb, node_b, hb, N_NODES, NODE_DIM);

    // ---- GIN layers ----
    for (int l = 0; l < N_LAYERS; ++l) {
        k_agg<<<(N_NODES + 3) / 4, 256, 0, stream>>>(hb, rowptr, col, eps, l, zb);
        k_gemm<<<ggrid, 256, 0, stream>>>(zb, w1b + (size_t)l * HIDDEN * HIDDEN, gb1 + (size_t)l * HIDDEN,
                                          tb, N_NODES, HIDDEN);
        k_gemm<<<ggrid, 256, 0, stream>>>(tb, w2b + (size_t)l * HIDDEN * HIDDEN, gb2 + (size_t)l * HIDDEN,
                                          hb, N_NODES, HIDDEN);
    }

    // ---- pooling + head ----
    dim3 pgrid(N_GRAPHS, POOL_CHUNKS);
    k_pool<<<pgrid, 256, 0, stream>>>(hb, starts, part);
    k_head<<<N_GRAPHS, 256, 0, stream>>>(part, starts, ow1, ob1, ow2, ob2, out);
}

// Round 4
// 1010.377 us; speedup vs baseline: 1.7517x; 1.2213x over previous
//
#include <hip/hip_runtime.h>
#include <stdint.h>

#define N_NODES   100000
#define N_EDGES   800000
#define NODE_DIM  128
#define HIDDEN    256
#define OUT_DIM   512
#define N_LAYERS  4
#define N_GRAPHS  64
#define POOL_CHUNKS 8
#define SCAN_BLK  1024
#define SCAN_NB   ((N_NODES + SCAN_BLK - 1) / SCAN_BLK)   // 98

typedef _Float16 f16;
typedef __attribute__((ext_vector_type(8))) _Float16 f16x8;
typedef __attribute__((ext_vector_type(4))) _Float16 f16x4;
typedef __attribute__((ext_vector_type(4))) float    f32x4;

// ---------------- fp32 -> fp16 conversion (vectorized) ----------------
__global__ void k_f2h(const float* __restrict__ in, f16* __restrict__ out, int n4) {
    int i = blockIdx.x * 256 + threadIdx.x;
    if (i < n4) {
        f32x4 v = *(const f32x4*)(in + (size_t)i * 4);
        f16x4 o;
        o[0] = (f16)v[0]; o[1] = (f16)v[1]; o[2] = (f16)v[2]; o[3] = (f16)v[3];
        *(f16x4*)(out + (size_t)i * 4) = o;
    }
}

// ---------------- CSR build: histogram over dst ----------------
__global__ void k_hist(const int* __restrict__ ei, int* __restrict__ deg) {
    int e = blockIdx.x * 256 + threadIdx.x;
    if (e < N_EDGES) atomicAdd(&deg[ei[N_EDGES + e]], 1);
}

// ---------------- CSR build: 3-phase device-wide exclusive scan ----------------
// Phase 1: per-block (1024-wide) Hillis-Steele; local exclusive prefix -> rowptr,
// block total -> bsums. Coalesced, 98 blocks in parallel.
__global__ __launch_bounds__(1024) void k_scan1(const int* __restrict__ deg,
                                                int* __restrict__ rowptr,
                                                int* __restrict__ bsums) {
    __shared__ int tmp[SCAN_BLK];
    int tid = threadIdx.x;
    int i = blockIdx.x * SCAN_BLK + tid;
    int v = (i < N_NODES) ? deg[i] : 0;
    tmp[tid] = v;
    __syncthreads();
    for (int off = 1; off < SCAN_BLK; off <<= 1) {
        int t = (tid >= off) ? tmp[tid - off] : 0;
        __syncthreads();
        tmp[tid] += t;
        __syncthreads();
    }
    if (i < N_NODES) rowptr[i] = tmp[tid] - v;        // local exclusive prefix
    if (tid == SCAN_BLK - 1) bsums[blockIdx.x] = tmp[tid];
}

// Phase 2: scan the 98 block sums (single tiny block).
__global__ __launch_bounds__(128) void k_scan2(const int* __restrict__ bsums,
                                               int* __restrict__ boffs,
                                               int* __restrict__ rowptr) {
    __shared__ int tmp[128];
    int tid = threadIdx.x;
    int v = (tid < SCAN_NB) ? bsums[tid] : 0;
    tmp[tid] = v;
    __syncthreads();
    for (int off = 1; off < 128; off <<= 1) {
        int t = (tid >= off) ? tmp[tid - off] : 0;
        __syncthreads();
        tmp[tid] += t;
        __syncthreads();
    }
    if (tid < SCAN_NB) boffs[tid] = tmp[tid] - v;     // exclusive block offset
    if (tid == 127) rowptr[N_NODES] = tmp[127];       // total = N_EDGES
}

// Phase 3: add block offsets; mirror into cursor.
__global__ __launch_bounds__(1024) void k_scan3(int* __restrict__ rowptr,
                                                const int* __restrict__ boffs,
                                                int* __restrict__ cursor) {
    int i = blockIdx.x * SCAN_BLK + threadIdx.x;
    if (i < N_NODES) {
        int r = rowptr[i] + boffs[blockIdx.x];
        rowptr[i] = r;
        cursor[i] = r;
    }
}

// ---------------- CSR build: scatter src into col ----------------
__global__ void k_scatter(const int* __restrict__ ei, int* __restrict__ cursor,
                          int* __restrict__ col) {
    int e = blockIdx.x * 256 + threadIdx.x;
    if (e < N_EDGES) {
        int d = ei[N_EDGES + e];
        int p = atomicAdd(&cursor[d], 1);
        col[p] = ei[e];
    }
}

// ---------------- aggregation: z = (1+eps)*h + sum_{s in N(v)} h[s], fp16 out ----------------
__global__ __launch_bounds__(256) void k_agg(const f16* __restrict__ h,
                                             const int* __restrict__ rowptr,
                                             const int* __restrict__ col,
                                             const float* __restrict__ eps, int layer,
                                             f16* __restrict__ z) {
    int node = blockIdx.x * 4 + (threadIdx.x >> 6);
    if (node >= N_NODES) return;
    int lane = threadIdx.x & 63;
    int c0 = lane * 4;                         // 64 lanes x 4 ch = 256
    float e1 = 1.0f + eps[layer];
    f16x4 hv = *(const f16x4*)(h + (size_t)node * HIDDEN + c0);
    float a0 = e1 * (float)hv[0], a1 = e1 * (float)hv[1];
    float a2 = e1 * (float)hv[2], a3 = e1 * (float)hv[3];
    int jb = rowptr[node], je = rowptr[node + 1];
    for (int j = jb; j < je; ++j) {
        int s = col[j];
        f16x4 v = *(const f16x4*)(h + (size_t)s * HIDDEN + c0);
        a0 += (float)v[0]; a1 += (float)v[1]; a2 += (float)v[2]; a3 += (float)v[3];
    }
    f16x4 o;
    o[0] = (f16)a0; o[1] = (f16)a1; o[2] = (f16)a2; o[3] = (f16)a3;
    *(f16x4*)(z + (size_t)node * HIDDEN + c0) = o;
}

// ---------------- GEMM: C[M][256] = relu(A[M][K] @ B[256][K]^T + bias), f16 in/out ----------------
// 128x128 tile, 4 waves (2x2), mfma_f32_16x16x32_f16, global_load_lds staging,
// T2 XOR-swizzle done via pre-swizzled GLOBAL source + swizzled ds_read (rule #21).
__global__ __launch_bounds__(256) void k_gemm(const f16* __restrict__ A,
                                              const f16* __restrict__ B,
                                              const float* __restrict__ bias,
                                              f16* __restrict__ C, int M, int K) {
    __shared__ f16 As[128 * 64];   // [row][64] fp16, 16 KB (stored source-swizzled)
    __shared__ f16 Bs[128 * 64];
    const int bm = blockIdx.x, bn = blockIdx.y;
    const int tid = threadIdx.x, wid = tid >> 6, lane = tid & 63;
    const int wr = wid >> 1, wc = wid & 1;     // 2x2 wave grid, each wave 64x64
    const int row0 = bm * 128, col0 = bn * 128;
    f32x4 acc[4][4] = {};

    for (int k0 = 0; k0 < K; k0 += 64) {
#pragma unroll
        for (int r = 0; r < 4; ++r) {
            int chunk = lane + (wid << 6) + (r << 8);    // 0..1023 16B chunks
            int arow = chunk >> 3;                        // 8 chunks per 128B row
            int c8   = chunk & 7;
            int sc8  = c8 ^ (arow & 7);                   // inverse-swizzled source col
            int gar  = row0 + arow; if (gar >= M) gar = M - 1;   // tail clamp (rows >= M discarded)
            const f16* srcA = A + (size_t)gar * K + k0 + sc8 * 8;
            const f16* srcB = B + (size_t)(col0 + arow) * K + k0 + sc8 * 8;
            f16* ldsbA = As + ((size_t)((wid << 6) + (r << 8))) * 8;  // wave-uniform base, lane*16 implicit
            f16* ldsbB = Bs + ((size_t)((wid << 6) + (r << 8))) * 8;
            __builtin_amdgcn_global_load_lds((const __attribute__((address_space(1))) void*)srcA,
                                             (__attribute__((address_space(3))) void*)ldsbA, 16, 0, 0);
            __builtin_amdgcn_global_load_lds((const __attribute__((address_space(1))) void*)srcB,
                                             (__attribute__((address_space(3))) void*)ldsbB, 16, 0, 0);
        }
        __syncthreads();
#pragma unroll
        for (int ks = 0; ks < 2; ++ks) {
            f16x8 af[4], bf[4];
            const int klo = (lane >> 4);                  // k-group 0..3
#pragma unroll
            for (int m = 0; m < 4; ++m) {
                int ra = wr * 64 + m * 16 + (lane & 15);
                af[m] = *(const f16x8*)(As + ra * 64 + ((((ks << 2) | klo) ^ (ra & 7)) << 3));
            }
#pragma unroll
            for (int n = 0; n < 4; ++n) {
                int rb = wc * 64 + n * 16 + (lane & 15);
                bf[n] = *(const f16x8*)(Bs + rb * 64 + ((((ks << 2) | klo) ^ (rb & 7)) << 3));
            }
#pragma unroll
            for (int m = 0; m < 4; ++m)
#pragma unroll
                for (int n = 0; n < 4; ++n)
                    acc[m][n] = __builtin_amdgcn_mfma_f32_16x16x32_f16(af[m], bf[n], acc[m][n], 0, 0, 0);
        }
        __syncthreads();
    }
    // epilogue: bias + relu + fp16 store. D: col=lane&15, row=(lane>>4)*4+j
#pragma unroll
    for (int n = 0; n < 4; ++n) {
        int gc = col0 + wc * 64 + n * 16 + (lane & 15);
        float bv = bias[gc];
#pragma unroll
        for (int m = 0; m < 4; ++m) {
            int gr0 = row0 + wr * 64 + m * 16 + ((lane >> 4) << 2);
#pragma unroll
            for (int j = 0; j < 4; ++j) {
                int gr = gr0 + j;
                if (gr < M) {
                    float v = acc[m][n][j] + bv;
                    v = fmaxf(v, 0.0f);
                    C[(size_t)gr * HIDDEN + gc] = (f16)v;
                }
            }
        }
    }
}

// ---------------- segment starts from sorted batch (atomic-free) ----------------
// starts[g] = first node index with batch >= g; starts[N_GRAPHS] = N_NODES.
__global__ void k_bounds(const int* __restrict__ batch, int* __restrict__ starts) {
    int i = blockIdx.x * 256 + threadIdx.x;
    if (i >= N_NODES) return;
    int g  = batch[i];
    int gp = (i == 0) ? -1 : batch[i - 1];
    for (int q = gp + 1; q <= g; ++q) starts[q] = i;
    if (i == N_NODES - 1) {
        for (int q = g + 1; q <= N_GRAPHS; ++q) starts[q] = N_NODES;
    }
}

// ---------------- pooled partial sums (atomic-free; batch sorted & contiguous) ----------------
__global__ __launch_bounds__(256) void k_pool(const f16* __restrict__ h,
                                              const int* __restrict__ starts,
                                              float* __restrict__ part) {
    int g = blockIdx.x, ch = blockIdx.y, c = threadIdx.x;
    int s = starts[g], e = starts[g + 1];
    int len = e - s;
    int per = (len + POOL_CHUNKS - 1) / POOL_CHUNKS;
    int lo = s + ch * per;
    int hi = lo + per; if (hi > e) hi = e;
    float acc = 0.0f;
    for (int n = lo; n < hi; ++n) acc += (float)h[(size_t)n * HIDDEN + c];
    part[((size_t)g * POOL_CHUNKS + ch) * HIDDEN + c] = acc;
}

// ---------------- head MLP (fp32, tiny) ----------------
__global__ __launch_bounds__(256) void k_head(const float* __restrict__ part,
                                              const int* __restrict__ starts,
                                              const float* __restrict__ w1,
                                              const float* __restrict__ b1,
                                              const float* __restrict__ w2,
                                              const float* __restrict__ b2,
                                              float* __restrict__ out) {
    __shared__ float hg[HIDDEN];
    __shared__ float t[HIDDEN];
    int g = blockIdx.x, tid = threadIdx.x;
    int cnti = starts[g + 1] - starts[g];
    float cnt = (float)(cnti > 1 ? cnti : 1);
    float s = 0.0f;
#pragma unroll
    for (int ch = 0; ch < POOL_CHUNKS; ++ch)
        s += part[((size_t)g * POOL_CHUNKS + ch) * HIDDEN + tid];
    hg[tid] = s / cnt;
    __syncthreads();
    float a = b1[tid];
    for (int k = 0; k < HIDDEN; ++k) a += hg[k] * w1[(size_t)tid * HIDDEN + k];
    t[tid] = fmaxf(a, 0.0f);
    __syncthreads();
    for (int j = tid; j < OUT_DIM; j += 256) {
        float o = b2[j];
        for (int k = 0; k < HIDDEN; ++k) o += t[k] * w2[(size_t)j * HIDDEN + k];
        out[(size_t)g * OUT_DIM + j] = o;
    }
}

extern "C" void kernel_launch(void* const* d_in, const int* in_sizes, int n_in,
                              void* d_out, int out_size, void* d_ws, size_t ws_size,
                              hipStream_t stream) {
    const float* x      = (const float*)d_in[0];
    const int*   ei     = (const int*)d_in[1];
    const int*   batch  = (const int*)d_in[2];
    const float* node_w = (const float*)d_in[3];
    const float* node_b = (const float*)d_in[4];
    const float* gw1    = (const float*)d_in[5];
    const float* gb1    = (const float*)d_in[6];
    const float* gw2    = (const float*)d_in[7];
    const float* gb2    = (const float*)d_in[8];
    const float* eps    = (const float*)d_in[9];
    const float* ow1    = (const float*)d_in[10];
    const float* ob1    = (const float*)d_in[11];
    const float* ow2    = (const float*)d_in[12];
    const float* ob2    = (const float*)d_in[13];
    float* out = (float*)d_out;

    // ---- workspace layout ----
    char* p = (char*)d_ws;
    auto alloc = [&](size_t bytes) {
        char* r = p;
        p += (bytes + 255) & ~(size_t)255;
        return (void*)r;
    };
    f16* hb   = (f16*)alloc((size_t)N_NODES * HIDDEN * 2);
    f16* zb   = (f16*)alloc((size_t)N_NODES * HIDDEN * 2);
    f16* tb   = (f16*)alloc((size_t)N_NODES * HIDDEN * 2);
    f16* xb   = (f16*)alloc((size_t)N_NODES * NODE_DIM * 2);
    f16* nwb  = (f16*)alloc((size_t)HIDDEN * NODE_DIM * 2);
    f16* w1b  = (f16*)alloc((size_t)N_LAYERS * HIDDEN * HIDDEN * 2);
    f16* w2b  = (f16*)alloc((size_t)N_LAYERS * HIDDEN * HIDDEN * 2);
    int* deg    = (int*)alloc((size_t)N_NODES * 4);
    int* rowptr = (int*)alloc((size_t)(N_NODES + 1) * 4);
    int* cursor = (int*)alloc((size_t)N_NODES * 4);
    int* col    = (int*)alloc((size_t)N_EDGES * 4);
    float* part = (float*)alloc((size_t)N_GRAPHS * POOL_CHUNKS * HIDDEN * 4);
    int* starts = (int*)alloc((size_t)(N_GRAPHS + 1) * 4);
    int* bsums  = (int*)alloc((size_t)SCAN_NB * 4);
    int* boffs  = (int*)alloc((size_t)SCAN_NB * 4);
    (void)in_sizes; (void)n_in; (void)out_size; (void)ws_size;

    // ---- zero what we accumulate into ----
    hipMemsetAsync(deg, 0, (size_t)N_NODES * 4, stream);

    // ---- fp16 conversions ----
    k_f2h<<<(N_NODES * NODE_DIM / 4 + 255) / 256, 256, 0, stream>>>(x, xb, N_NODES * NODE_DIM / 4);
    k_f2h<<<(HIDDEN * NODE_DIM / 4 + 255) / 256, 256, 0, stream>>>(node_w, nwb, HIDDEN * NODE_DIM / 4);
    k_f2h<<<(N_LAYERS * HIDDEN * HIDDEN / 4 + 255) / 256, 256, 0, stream>>>(gw1, w1b, N_LAYERS * HIDDEN * HIDDEN / 4);
    k_f2h<<<(N_LAYERS * HIDDEN * HIDDEN / 4 + 255) / 256, 256, 0, stream>>>(gw2, w2b, N_LAYERS * HIDDEN * HIDDEN / 4);

    // ---- CSR build ----
    k_hist<<<(N_EDGES + 255) / 256, 256, 0, stream>>>(ei, deg);
    k_scan1<<<SCAN_NB, SCAN_BLK, 0, stream>>>(deg, rowptr, bsums);
    k_scan2<<<1, 128, 0, stream>>>(bsums, boffs, rowptr);
    k_scan3<<<SCAN_NB, SCAN_BLK, 0, stream>>>(rowptr, boffs, cursor);
    k_scatter<<<(N_EDGES + 255) / 256, 256, 0, stream>>>(ei, cursor, col);

    // ---- segment bounds ----
    k_bounds<<<(N_NODES + 255) / 256, 256, 0, stream>>>(batch, starts);

    // ---- node projection ----
    dim3 ggrid((N_NODES + 127) / 128, HIDDEN / 128);
    k_gemm<<<ggrid, 256, 0, stream>>>(xb, nwb, node_b, hb, N_NODES, NODE_DIM);

    // ---- GIN layers ----
    for (int l = 0; l < N_LAYERS; ++l) {
        k_agg<<<(N_NODES + 3) / 4, 256, 0, stream>>>(hb, rowptr, col, eps, l, zb);
        k_gemm<<<ggrid, 256, 0, stream>>>(zb, w1b + (size_t)l * HIDDEN * HIDDEN, gb1 + (size_t)l * HIDDEN,
                                          tb, N_NODES, HIDDEN);
        k_gemm<<<ggrid, 256, 0, stream>>>(tb, w2b + (size_t)l * HIDDEN * HIDDEN, gb2 + (size_t)l * HIDDEN,
                                          hb, N_NODES, HIDDEN);
    }

    // ---- pooling + head ----
    dim3 pgrid(N_GRAPHS, POOL_CHUNKS);
    k_pool<<<pgrid, 256, 0, stream>>>(hb, starts, part);
    k_head<<<N_GRAPHS, 256, 0, stream>>>(part, starts, ow1, ob1, ow2, ob2, out);
}

// Round 5
// 996.037 us; speedup vs baseline: 1.7769x; 1.0144x over previous
//
#include <hip/hip_runtime.h>
#include <stdint.h>

#define N_NODES   100000
#define N_EDGES   800000
#define NODE_DIM  128
#define HIDDEN    256
#define OUT_DIM   512
#define N_LAYERS  4
#define N_GRAPHS  64
#define POOL_CHUNKS 8
#define SCAN_BLK  1024
#define SCAN_NB   ((N_NODES + SCAN_BLK - 1) / SCAN_BLK)   // 98

typedef _Float16 f16;
typedef __attribute__((ext_vector_type(8))) _Float16 f16x8;
typedef __attribute__((ext_vector_type(4))) _Float16 f16x4;
typedef __attribute__((ext_vector_type(4))) float    f32x4;

// ---------------- fp32 -> fp16 conversion (vectorized) ----------------
__global__ void k_f2h(const float* __restrict__ in, f16* __restrict__ out, int n4) {
    int i = blockIdx.x * 256 + threadIdx.x;
    if (i < n4) {
        f32x4 v = *(const f32x4*)(in + (size_t)i * 4);
        f16x4 o;
        o[0] = (f16)v[0]; o[1] = (f16)v[1]; o[2] = (f16)v[2]; o[3] = (f16)v[3];
        *(f16x4*)(out + (size_t)i * 4) = o;
    }
}

// ---------------- CSR build: histogram over dst ----------------
__global__ void k_hist(const int* __restrict__ ei, int* __restrict__ deg) {
    int e = blockIdx.x * 256 + threadIdx.x;
    if (e < N_EDGES) atomicAdd(&deg[ei[N_EDGES + e]], 1);
}

// ---------------- CSR build: 3-phase device-wide exclusive scan ----------------
__global__ __launch_bounds__(1024) void k_scan1(const int* __restrict__ deg,
                                                int* __restrict__ rowptr,
                                                int* __restrict__ bsums) {
    __shared__ int tmp[SCAN_BLK];
    int tid = threadIdx.x;
    int i = blockIdx.x * SCAN_BLK + tid;
    int v = (i < N_NODES) ? deg[i] : 0;
    tmp[tid] = v;
    __syncthreads();
    for (int off = 1; off < SCAN_BLK; off <<= 1) {
        int t = (tid >= off) ? tmp[tid - off] : 0;
        __syncthreads();
        tmp[tid] += t;
        __syncthreads();
    }
    if (i < N_NODES) rowptr[i] = tmp[tid] - v;        // local exclusive prefix
    if (tid == SCAN_BLK - 1) bsums[blockIdx.x] = tmp[tid];
}

__global__ __launch_bounds__(128) void k_scan2(const int* __restrict__ bsums,
                                               int* __restrict__ boffs,
                                               int* __restrict__ rowptr) {
    __shared__ int tmp[128];
    int tid = threadIdx.x;
    int v = (tid < SCAN_NB) ? bsums[tid] : 0;
    tmp[tid] = v;
    __syncthreads();
    for (int off = 1; off < 128; off <<= 1) {
        int t = (tid >= off) ? tmp[tid - off] : 0;
        __syncthreads();
        tmp[tid] += t;
        __syncthreads();
    }
    if (tid < SCAN_NB) boffs[tid] = tmp[tid] - v;     // exclusive block offset
    if (tid == 127) rowptr[N_NODES] = tmp[127];       // total = N_EDGES
}

__global__ __launch_bounds__(1024) void k_scan3(int* __restrict__ rowptr,
                                                const int* __restrict__ boffs,
                                                int* __restrict__ cursor) {
    int i = blockIdx.x * SCAN_BLK + threadIdx.x;
    if (i < N_NODES) {
        int r = rowptr[i] + boffs[blockIdx.x];
        rowptr[i] = r;
        cursor[i] = r;
    }
}

// ---------------- CSR build: scatter src into col ----------------
__global__ void k_scatter(const int* __restrict__ ei, int* __restrict__ cursor,
                          int* __restrict__ col) {
    int e = blockIdx.x * 256 + threadIdx.x;
    if (e < N_EDGES) {
        int d = ei[N_EDGES + e];
        int p = atomicAdd(&cursor[d], 1);
        col[p] = ei[e];
    }
}

// ---------------- aggregation: z = (1+eps)*h + sum_{s in N(v)} h[s], fp16 out ----------------
__global__ __launch_bounds__(256) void k_agg(const f16* __restrict__ h,
                                             const int* __restrict__ rowptr,
                                             const int* __restrict__ col,
                                             const float* __restrict__ eps, int layer,
                                             f16* __restrict__ z) {
    int node = blockIdx.x * 4 + (threadIdx.x >> 6);
    if (node >= N_NODES) return;
    int lane = threadIdx.x & 63;
    int c0 = lane * 4;                         // 64 lanes x 4 ch = 256
    float e1 = 1.0f + eps[layer];
    f16x4 hv = *(const f16x4*)(h + (size_t)node * HIDDEN + c0);
    float a0 = e1 * (float)hv[0], a1 = e1 * (float)hv[1];
    float a2 = e1 * (float)hv[2], a3 = e1 * (float)hv[3];
    int jb = rowptr[node], je = rowptr[node + 1];
    for (int j = jb; j < je; ++j) {
        int s = col[j];
        f16x4 v = *(const f16x4*)(h + (size_t)s * HIDDEN + c0);
        a0 += (float)v[0]; a1 += (float)v[1]; a2 += (float)v[2]; a3 += (float)v[3];
    }
    f16x4 o;
    o[0] = (f16)a0; o[1] = (f16)a1; o[2] = (f16)a2; o[3] = (f16)a3;
    *(f16x4*)(z + (size_t)node * HIDDEN + c0) = o;
}

// ---------------- GEMM: C[M][256] = relu(A[M][K] @ B[256][K]^T + bias), f16 in/out ----------------
// Wide-N: 64x256 block tile, 4 waves (1x4), each wave 64x64. A read ONCE per GEMM.
// As 8KB + Bs 32KB = 40KB LDS. XOR-swizzle via pre-swizzled global source (rule #21).
__global__ __launch_bounds__(256) void k_gemm(const f16* __restrict__ A,
                                              const f16* __restrict__ B,
                                              const float* __restrict__ bias,
                                              f16* __restrict__ C, int M, int K) {
    __shared__ f16 As[64 * 64];    // 8 KB
    __shared__ f16 Bs[256 * 64];   // 32 KB
    const int bm = blockIdx.x;
    const int tid = threadIdx.x, wid = tid >> 6, lane = tid & 63;
    const int row0 = bm * 64;
    f32x4 acc[4][4] = {};

    for (int k0 = 0; k0 < K; k0 += 64) {
        // stage As: 512 x 16B chunks, 2 per thread
#pragma unroll
        for (int r = 0; r < 2; ++r) {
            int chunk = (r << 8) + (wid << 6) + lane;     // 0..511
            int arow = chunk >> 3, c8 = chunk & 7;
            int sc8  = c8 ^ (arow & 7);
            int gar  = row0 + arow; if (gar >= M) gar = M - 1;
            const f16* srcA = A + (size_t)gar * K + k0 + sc8 * 8;
            f16* ldsbA = As + (size_t)((r << 8) + (wid << 6)) * 8;
            __builtin_amdgcn_global_load_lds((const __attribute__((address_space(1))) void*)srcA,
                                             (__attribute__((address_space(3))) void*)ldsbA, 16, 0, 0);
        }
        // stage Bs: 2048 x 16B chunks, 8 per thread (B rows = all 256 output cols)
#pragma unroll
        for (int r = 0; r < 8; ++r) {
            int chunk = (r << 8) + (wid << 6) + lane;     // 0..2047
            int brow = chunk >> 3, c8 = chunk & 7;
            int sc8  = c8 ^ (brow & 7);
            const f16* srcB = B + (size_t)brow * K + k0 + sc8 * 8;
            f16* ldsbB = Bs + (size_t)((r << 8) + (wid << 6)) * 8;
            __builtin_amdgcn_global_load_lds((const __attribute__((address_space(1))) void*)srcB,
                                             (__attribute__((address_space(3))) void*)ldsbB, 16, 0, 0);
        }
        __syncthreads();
#pragma unroll
        for (int ks = 0; ks < 2; ++ks) {
            const int klo = (lane >> 4);                  // k-group 0..3
            f16x8 af[4], bf[4];
#pragma unroll
            for (int m = 0; m < 4; ++m) {
                int ra = m * 16 + (lane & 15);
                af[m] = *(const f16x8*)(As + ra * 64 + ((((ks << 2) | klo) ^ (ra & 7)) << 3));
            }
#pragma unroll
            for (int n = 0; n < 4; ++n) {
                int rb = wid * 64 + n * 16 + (lane & 15);
                bf[n] = *(const f16x8*)(Bs + rb * 64 + ((((ks << 2) | klo) ^ (rb & 7)) << 3));
            }
#pragma unroll
            for (int m = 0; m < 4; ++m)
#pragma unroll
                for (int n = 0; n < 4; ++n)
                    acc[m][n] = __builtin_amdgcn_mfma_f32_16x16x32_f16(af[m], bf[n], acc[m][n], 0, 0, 0);
        }
        __syncthreads();
    }
    // epilogue: bias + relu + fp16 store. D: col=lane&15, row=(lane>>4)*4+j
#pragma unroll
    for (int n = 0; n < 4; ++n) {
        int gc = wid * 64 + n * 16 + (lane & 15);
        float bv = bias[gc];
#pragma unroll
        for (int m = 0; m < 4; ++m) {
            int gr0 = row0 + m * 16 + ((lane >> 4) << 2);
#pragma unroll
            for (int j = 0; j < 4; ++j) {
                int gr = gr0 + j;
                if (gr < M) {
                    float v = acc[m][n][j] + bv;
                    v = fmaxf(v, 0.0f);
                    C[(size_t)gr * HIDDEN + gc] = (f16)v;
                }
            }
        }
    }
}

// ---------------- segment starts from sorted batch (atomic-free) ----------------
__global__ void k_bounds(const int* __restrict__ batch, int* __restrict__ starts) {
    int i = blockIdx.x * 256 + threadIdx.x;
    if (i >= N_NODES) return;
    int g  = batch[i];
    int gp = (i == 0) ? -1 : batch[i - 1];
    for (int q = gp + 1; q <= g; ++q) starts[q] = i;
    if (i == N_NODES - 1) {
        for (int q = g + 1; q <= N_GRAPHS; ++q) starts[q] = N_NODES;
    }
}

// ---------------- pooled partial sums (atomic-free; batch sorted & contiguous) ----------------
__global__ __launch_bounds__(256) void k_pool(const f16* __restrict__ h,
                                              const int* __restrict__ starts,
                                              float* __restrict__ part) {
    int g = blockIdx.x, ch = blockIdx.y, c = threadIdx.x;
    int s = starts[g], e = starts[g + 1];
    int len = e - s;
    int per = (len + POOL_CHUNKS - 1) / POOL_CHUNKS;
    int lo = s + ch * per;
    int hi = lo + per; if (hi > e) hi = e;
    float acc = 0.0f;
    for (int n = lo; n < hi; ++n) acc += (float)h[(size_t)n * HIDDEN + c];
    part[((size_t)g * POOL_CHUNKS + ch) * HIDDEN + c] = acc;
}

// ---------------- head MLP (fp32, tiny) ----------------
__global__ __launch_bounds__(256) void k_head(const float* __restrict__ part,
                                              const int* __restrict__ starts,
                                              const float* __restrict__ w1,
                                              const float* __restrict__ b1,
                                              const float* __restrict__ w2,
                                              const float* __restrict__ b2,
                                              float* __restrict__ out) {
    __shared__ float hg[HIDDEN];
    __shared__ float t[HIDDEN];
    int g = blockIdx.x, tid = threadIdx.x;
    int cnti = starts[g + 1] - starts[g];
    float cnt = (float)(cnti > 1 ? cnti : 1);
    float s = 0.0f;
#pragma unroll
    for (int ch = 0; ch < POOL_CHUNKS; ++ch)
        s += part[((size_t)g * POOL_CHUNKS + ch) * HIDDEN + tid];
    hg[tid] = s / cnt;
    __syncthreads();
    float a = b1[tid];
    for (int k = 0; k < HIDDEN; ++k) a += hg[k] * w1[(size_t)tid * HIDDEN + k];
    t[tid] = fmaxf(a, 0.0f);
    __syncthreads();
    for (int j = tid; j < OUT_DIM; j += 256) {
        float o = b2[j];
        for (int k = 0; k < HIDDEN; ++k) o += t[k] * w2[(size_t)j * HIDDEN + k];
        out[(size_t)g * OUT_DIM + j] = o;
    }
}

extern "C" void kernel_launch(void* const* d_in, const int* in_sizes, int n_in,
                              void* d_out, int out_size, void* d_ws, size_t ws_size,
                              hipStream_t stream) {
    const float* x      = (const float*)d_in[0];
    const int*   ei     = (const int*)d_in[1];
    const int*   batch  = (const int*)d_in[2];
    const float* node_w = (const float*)d_in[3];
    const float* node_b = (const float*)d_in[4];
    const float* gw1    = (const float*)d_in[5];
    const float* gb1    = (const float*)d_in[6];
    const float* gw2    = (const float*)d_in[7];
    const float* gb2    = (const float*)d_in[8];
    const float* eps    = (const float*)d_in[9];
    const float* ow1    = (const float*)d_in[10];
    const float* ob1    = (const float*)d_in[11];
    const float* ow2    = (const float*)d_in[12];
    const float* ob2    = (const float*)d_in[13];
    float* out = (float*)d_out;

    // ---- workspace layout ----
    char* p = (char*)d_ws;
    auto alloc = [&](size_t bytes) {
        char* r = p;
        p += (bytes + 255) & ~(size_t)255;
        return (void*)r;
    };
    f16* hb   = (f16*)alloc((size_t)N_NODES * HIDDEN * 2);
    f16* zb   = (f16*)alloc((size_t)N_NODES * HIDDEN * 2);
    f16* tb   = (f16*)alloc((size_t)N_NODES * HIDDEN * 2);
    f16* xb   = (f16*)alloc((size_t)N_NODES * NODE_DIM * 2);
    f16* nwb  = (f16*)alloc((size_t)HIDDEN * NODE_DIM * 2);
    f16* w1b  = (f16*)alloc((size_t)N_LAYERS * HIDDEN * HIDDEN * 2);
    f16* w2b  = (f16*)alloc((size_t)N_LAYERS * HIDDEN * HIDDEN * 2);
    int* deg    = (int*)alloc((size_t)N_NODES * 4);
    int* rowptr = (int*)alloc((size_t)(N_NODES + 1) * 4);
    int* cursor = (int*)alloc((size_t)N_NODES * 4);
    int* col    = (int*)alloc((size_t)N_EDGES * 4);
    float* part = (float*)alloc((size_t)N_GRAPHS * POOL_CHUNKS * HIDDEN * 4);
    int* starts = (int*)alloc((size_t)(N_GRAPHS + 1) * 4);
    int* bsums  = (int*)alloc((size_t)SCAN_NB * 4);
    int* boffs  = (int*)alloc((size_t)SCAN_NB * 4);
    (void)in_sizes; (void)n_in; (void)out_size; (void)ws_size;

    // ---- zero what we accumulate into ----
    hipMemsetAsync(deg, 0, (size_t)N_NODES * 4, stream);

    // ---- fp16 conversions ----
    k_f2h<<<(N_NODES * NODE_DIM / 4 + 255) / 256, 256, 0, stream>>>(x, xb, N_NODES * NODE_DIM / 4);
    k_f2h<<<(HIDDEN * NODE_DIM / 4 + 255) / 256, 256, 0, stream>>>(node_w, nwb, HIDDEN * NODE_DIM / 4);
    k_f2h<<<(N_LAYERS * HIDDEN * HIDDEN / 4 + 255) / 256, 256, 0, stream>>>(gw1, w1b, N_LAYERS * HIDDEN * HIDDEN / 4);
    k_f2h<<<(N_LAYERS * HIDDEN * HIDDEN / 4 + 255) / 256, 256, 0, stream>>>(gw2, w2b, N_LAYERS * HIDDEN * HIDDEN / 4);

    // ---- CSR build ----
    k_hist<<<(N_EDGES + 255) / 256, 256, 0, stream>>>(ei, deg);
    k_scan1<<<SCAN_NB, SCAN_BLK, 0, stream>>>(deg, rowptr, bsums);
    k_scan2<<<1, 128, 0, stream>>>(bsums, boffs, rowptr);
    k_scan3<<<SCAN_NB, SCAN_BLK, 0, stream>>>(rowptr, boffs, cursor);
    k_scatter<<<(N_EDGES + 255) / 256, 256, 0, stream>>>(ei, cursor, col);

    // ---- segment bounds ----
    k_bounds<<<(N_NODES + 255) / 256, 256, 0, stream>>>(batch, starts);

    // ---- node projection ----
    const int GB = (N_NODES + 63) / 64;   // 1563
    k_gemm<<<GB, 256, 0, stream>>>(xb, nwb, node_b, hb, N_NODES, NODE_DIM);

    // ---- GIN layers ----
    for (int l = 0; l < N_LAYERS; ++l) {
        k_agg<<<(N_NODES + 3) / 4, 256, 0, stream>>>(hb, rowptr, col, eps, l, zb);
        k_gemm<<<GB, 256, 0, stream>>>(zb, w1b + (size_t)l * HIDDEN * HIDDEN, gb1 + (size_t)l * HIDDEN,
                                       tb, N_NODES, HIDDEN);
        k_gemm<<<GB, 256, 0, stream>>>(tb, w2b + (size_t)l * HIDDEN * HIDDEN, gb2 + (size_t)l * HIDDEN,
                                       hb, N_NODES, HIDDEN);
    }

    // ---- pooling + head ----
    dim3 pgrid(N_GRAPHS, POOL_CHUNKS);
    k_pool<<<pgrid, 256, 0, stream>>>(hb, starts, part);
    k_head<<<N_GRAPHS, 256, 0, stream>>>(part, starts, ow1, ob1, ow2, ob2, out);
}

// Round 8
// 798.859 us; speedup vs baseline: 2.2155x; 1.2468x over previous
//
#include <hip/hip_runtime.h>
#include <stdint.h>

#define N_NODES   100000
#define N_EDGES   800000
#define NODE_DIM  128
#define HIDDEN    256
#define OUT_DIM   512
#define N_LAYERS  4
#define N_GRAPHS  64
#define POOL_CHUNKS 8
#define SCAN_BLK  1024
#define SCAN_NB   ((N_NODES + SCAN_BLK - 1) / SCAN_BLK)   // 98

typedef _Float16 f16;
typedef __attribute__((ext_vector_type(8))) _Float16 f16x8;
typedef __attribute__((ext_vector_type(4))) _Float16 f16x4;
typedef __attribute__((ext_vector_type(4))) float    f32x4;

// ---------------- fp32 -> fp16 conversion (vectorized) ----------------
__global__ void k_f2h(const float* __restrict__ in, f16* __restrict__ out, int n4) {
    int i = blockIdx.x * 256 + threadIdx.x;
    if (i < n4) {
        f32x4 v = *(const f32x4*)(in + (size_t)i * 4);
        f16x4 o;
        o[0] = (f16)v[0]; o[1] = (f16)v[1]; o[2] = (f16)v[2]; o[3] = (f16)v[3];
        *(f16x4*)(out + (size_t)i * 4) = o;
    }
}

// ---------------- CSR build: histogram over dst ----------------
__global__ void k_hist(const int* __restrict__ ei, int* __restrict__ deg) {
    int e = blockIdx.x * 256 + threadIdx.x;
    if (e < N_EDGES) atomicAdd(&deg[ei[N_EDGES + e]], 1);
}

// ---------------- CSR build: 3-phase device-wide exclusive scan ----------------
__global__ __launch_bounds__(1024) void k_scan1(const int* __restrict__ deg,
                                                int* __restrict__ rowptr,
                                                int* __restrict__ bsums) {
    __shared__ int tmp[SCAN_BLK];
    int tid = threadIdx.x;
    int i = blockIdx.x * SCAN_BLK + tid;
    int v = (i < N_NODES) ? deg[i] : 0;
    tmp[tid] = v;
    __syncthreads();
    for (int off = 1; off < SCAN_BLK; off <<= 1) {
        int t = (tid >= off) ? tmp[tid - off] : 0;
        __syncthreads();
        tmp[tid] += t;
        __syncthreads();
    }
    if (i < N_NODES) rowptr[i] = tmp[tid] - v;        // local exclusive prefix
    if (tid == SCAN_BLK - 1) bsums[blockIdx.x] = tmp[tid];
}

__global__ __launch_bounds__(128) void k_scan2(const int* __restrict__ bsums,
                                               int* __restrict__ boffs,
                                               int* __restrict__ rowptr) {
    __shared__ int tmp[128];
    int tid = threadIdx.x;
    int v = (tid < SCAN_NB) ? bsums[tid] : 0;
    tmp[tid] = v;
    __syncthreads();
    for (int off = 1; off < 128; off <<= 1) {
        int t = (tid >= off) ? tmp[tid - off] : 0;
        __syncthreads();
        tmp[tid] += t;
        __syncthreads();
    }
    if (tid < SCAN_NB) boffs[tid] = tmp[tid] - v;     // exclusive block offset
    if (tid == 127) rowptr[N_NODES] = tmp[127];       // total = N_EDGES
}

__global__ __launch_bounds__(1024) void k_scan3(int* __restrict__ rowptr,
                                                const int* __restrict__ boffs,
                                                int* __restrict__ cursor) {
    int i = blockIdx.x * SCAN_BLK + threadIdx.x;
    if (i < N_NODES) {
        int r = rowptr[i] + boffs[blockIdx.x];
        rowptr[i] = r;
        cursor[i] = r;
    }
}

// ---------------- CSR build: scatter src into col ----------------
__global__ void k_scatter(const int* __restrict__ ei, int* __restrict__ cursor,
                          int* __restrict__ col) {
    int e = blockIdx.x * 256 + threadIdx.x;
    if (e < N_EDGES) {
        int d = ei[N_EDGES + e];
        int p = atomicAdd(&cursor[d], 1);
        col[p] = ei[e];
    }
}

// ---------------- aggregation: z = (1+eps)*h + sum_{s in N(v)} h[s], fp16 out ----------------
__global__ __launch_bounds__(256) void k_agg(const f16* __restrict__ h,
                                             const int* __restrict__ rowptr,
                                             const int* __restrict__ col,
                                             const float* __restrict__ eps, int layer,
                                             f16* __restrict__ z) {
    int node = blockIdx.x * 4 + (threadIdx.x >> 6);
    if (node >= N_NODES) return;
    int lane = threadIdx.x & 63;
    int c0 = lane * 4;                         // 64 lanes x 4 ch = 256
    float e1 = 1.0f + eps[layer];
    f16x4 hv = *(const f16x4*)(h + (size_t)node * HIDDEN + c0);
    float a0 = e1 * (float)hv[0], a1 = e1 * (float)hv[1];
    float a2 = e1 * (float)hv[2], a3 = e1 * (float)hv[3];
    int jb = rowptr[node], je = rowptr[node + 1];
    for (int j = jb; j < je; ++j) {
        int s = col[j];
        f16x4 v = *(const f16x4*)(h + (size_t)s * HIDDEN + c0);
        a0 += (float)v[0]; a1 += (float)v[1]; a2 += (float)v[2]; a3 += (float)v[3];
    }
    f16x4 o;
    o[0] = (f16)a0; o[1] = (f16)a1; o[2] = (f16)a2; o[3] = (f16)a3;
    *(f16x4*)(z + (size_t)node * HIDDEN + c0) = o;
}

// ---------------- B-resident GEMM: C[M][256] = relu(A[M][K]@B[256][K]^T + bias) ----------------
// 512 threads (8 waves), B entirely in LDS (K/64 panels of [256][64], XOR-swizzled,
// staged once via global_load_lds). Barrier-FREE persistent slab loop: each wave owns
// 32 rows/slab, A-fragments prefetched global->VGPR (64B-line coalesced), 256 MFMA +
// 128 ds_read_b128 per slab with zero syncs. K templated so all frag arrays are
// statically indexed (no scratch).
template<int K>
__global__ __launch_bounds__(512) void k_gemm(const f16* __restrict__ A,
                                              const f16* __restrict__ B,
                                              const float* __restrict__ bias,
                                              f16* __restrict__ C, int M, int nslab) {
    constexpr int NPANEL = K >> 6;           // 2 (K=128) or 4 (K=256)
    constexpr int NKS    = K >> 5;           // 4 or 8 K-steps of 32
    __shared__ f16 Bs[NPANEL * 256 * 64];    // 64 or 128 KB
    const int tid = threadIdx.x, wid = tid >> 6, lane = tid & 63;
    const int klo = lane >> 4;               // k-group 0..3
    const int l15 = lane & 15;

    // ---- stage all of B once (swizzled via pre-swizzled global source) ----
#pragma unroll
    for (int p = 0; p < NPANEL; ++p) {
#pragma unroll
        for (int r = 0; r < 4; ++r) {
            int chunk = (r << 9) + tid;                  // 0..2047 within panel
            int brow = chunk >> 3, c8 = chunk & 7;
            int sc8  = c8 ^ (brow & 7);
            const f16* src = B + (size_t)brow * K + (p << 6) + sc8 * 8;
            f16* dst = Bs + (p << 14) + (size_t)((r << 9) + (wid << 6)) * 8;
            __builtin_amdgcn_global_load_lds((const __attribute__((address_space(1))) void*)src,
                                             (__attribute__((address_space(3))) void*)dst, 16, 0, 0);
        }
    }
    __syncthreads();   // ONLY barrier in the kernel

    // ---- persistent loop over 256-row slabs; wave owns rows [r0, r0+32) ----
    for (int slab = blockIdx.x; slab < nslab; slab += gridDim.x) {
        const int r0 = slab * 256 + wid * 32;
        // prefetch all A fragments for 32 rows x K
        f16x8 a[2][NKS];
#pragma unroll
        for (int m = 0; m < 2; ++m) {
            int gr = r0 + m * 16 + l15; if (gr >= M) gr = M - 1;
            const f16* arow = A + (size_t)gr * K + (klo << 3);
#pragma unroll
            for (int ks = 0; ks < NKS; ++ks)
                a[m][ks] = *(const f16x8*)(arow + (ks << 5));
        }
        f32x4 acc[2][16] = {};
#pragma unroll
        for (int ks = 0; ks < NKS; ++ks) {
            const int kk = ((ks & 1) << 2) | klo;
            const f16* pb = Bs + ((ks >> 1) << 14);
#pragma unroll
            for (int n = 0; n < 16; ++n) {
                int rb = (n << 4) + l15;
                f16x8 bf = *(const f16x8*)(pb + rb * 64 + ((kk ^ (rb & 7)) << 3));
                acc[0][n] = __builtin_amdgcn_mfma_f32_16x16x32_f16(a[0][ks], bf, acc[0][n], 0, 0, 0);
                acc[1][n] = __builtin_amdgcn_mfma_f32_16x16x32_f16(a[1][ks], bf, acc[1][n], 0, 0, 0);
            }
        }
        // epilogue: bias + relu + fp16 store. D: col=lane&15, row=(lane>>4)*4+j
#pragma unroll
        for (int n = 0; n < 16; ++n) {
            int gc = (n << 4) + l15;
            float bv = bias[gc];
#pragma unroll
            for (int m = 0; m < 2; ++m) {
                int gr0 = r0 + (m << 4) + (klo << 2);
#pragma unroll
                for (int j = 0; j < 4; ++j) {
                    int gr = gr0 + j;
                    if (gr < M) {
                        float v = fmaxf(acc[m][n][j] + bv, 0.0f);
                        C[(size_t)gr * HIDDEN + gc] = (f16)v;
                    }
                }
            }
        }
    }
}

// ---------------- segment starts from sorted batch (atomic-free) ----------------
__global__ void k_bounds(const int* __restrict__ batch, int* __restrict__ starts) {
    int i = blockIdx.x * 256 + threadIdx.x;
    if (i >= N_NODES) return;
    int g  = batch[i];
    int gp = (i == 0) ? -1 : batch[i - 1];
    for (int q = gp + 1; q <= g; ++q) starts[q] = i;
    if (i == N_NODES - 1) {
        for (int q = g + 1; q <= N_GRAPHS; ++q) starts[q] = N_NODES;
    }
}

// ---------------- pooled partial sums (atomic-free; batch sorted & contiguous) ----------------
__global__ __launch_bounds__(256) void k_pool(const f16* __restrict__ h,
                                              const int* __restrict__ starts,
                                              float* __restrict__ part) {
    int g = blockIdx.x, ch = blockIdx.y, c = threadIdx.x;
    int s = starts[g], e = starts[g + 1];
    int len = e - s;
    int per = (len + POOL_CHUNKS - 1) / POOL_CHUNKS;
    int lo = s + ch * per;
    int hi = lo + per; if (hi > e) hi = e;
    float acc = 0.0f;
    for (int n = lo; n < hi; ++n) acc += (float)h[(size_t)n * HIDDEN + c];
    part[((size_t)g * POOL_CHUNKS + ch) * HIDDEN + c] = acc;
}

// ---------------- head MLP (fp32, tiny) ----------------
__global__ __launch_bounds__(256) void k_head(const float* __restrict__ part,
                                              const int* __restrict__ starts,
                                              const float* __restrict__ w1,
                                              const float* __restrict__ b1,
                                              const float* __restrict__ w2,
                                              const float* __restrict__ b2,
                                              float* __restrict__ out) {
    __shared__ float hg[HIDDEN];
    __shared__ float t[HIDDEN];
    int g = blockIdx.x, tid = threadIdx.x;
    int cnti = starts[g + 1] - starts[g];
    float cnt = (float)(cnti > 1 ? cnti : 1);
    float s = 0.0f;
#pragma unroll
    for (int ch = 0; ch < POOL_CHUNKS; ++ch)
        s += part[((size_t)g * POOL_CHUNKS + ch) * HIDDEN + tid];
    hg[tid] = s / cnt;
    __syncthreads();
    float a = b1[tid];
    for (int k = 0; k < HIDDEN; ++k) a += hg[k] * w1[(size_t)tid * HIDDEN + k];
    t[tid] = fmaxf(a, 0.0f);
    __syncthreads();
    for (int j = tid; j < OUT_DIM; j += 256) {
        float o = b2[j];
        for (int k = 0; k < HIDDEN; ++k) o += t[k] * w2[(size_t)j * HIDDEN + k];
        out[(size_t)g * OUT_DIM + j] = o;
    }
}

extern "C" void kernel_launch(void* const* d_in, const int* in_sizes, int n_in,
                              void* d_out, int out_size, void* d_ws, size_t ws_size,
                              hipStream_t stream) {
    const float* x      = (const float*)d_in[0];
    const int*   ei     = (const int*)d_in[1];
    const int*   batch  = (const int*)d_in[2];
    const float* node_w = (const float*)d_in[3];
    const float* node_b = (const float*)d_in[4];
    const float* gw1    = (const float*)d_in[5];
    const float* gb1    = (const float*)d_in[6];
    const float* gw2    = (const float*)d_in[7];
    const float* gb2    = (const float*)d_in[8];
    const float* eps    = (const float*)d_in[9];
    const float* ow1    = (const float*)d_in[10];
    const float* ob1    = (const float*)d_in[11];
    const float* ow2    = (const float*)d_in[12];
    const float* ob2    = (const float*)d_in[13];
    float* out = (float*)d_out;

    // ---- workspace layout ----
    char* p = (char*)d_ws;
    auto alloc = [&](size_t bytes) {
        char* r = p;
        p += (bytes + 255) & ~(size_t)255;
        return (void*)r;
    };
    f16* hb   = (f16*)alloc((size_t)N_NODES * HIDDEN * 2);
    f16* zb   = (f16*)alloc((size_t)N_NODES * HIDDEN * 2);
    f16* tb   = (f16*)alloc((size_t)N_NODES * HIDDEN * 2);
    f16* xb   = (f16*)alloc((size_t)N_NODES * NODE_DIM * 2);
    f16* nwb  = (f16*)alloc((size_t)HIDDEN * NODE_DIM * 2);
    f16* w1b  = (f16*)alloc((size_t)N_LAYERS * HIDDEN * HIDDEN * 2);
    f16* w2b  = (f16*)alloc((size_t)N_LAYERS * HIDDEN * HIDDEN * 2);
    int* deg    = (int*)alloc((size_t)N_NODES * 4);
    int* rowptr = (int*)alloc((size_t)(N_NODES + 1) * 4);
    int* cursor = (int*)alloc((size_t)N_NODES * 4);
    int* col    = (int*)alloc((size_t)N_EDGES * 4);
    float* part = (float*)alloc((size_t)N_GRAPHS * POOL_CHUNKS * HIDDEN * 4);
    int* starts = (int*)alloc((size_t)(N_GRAPHS + 1) * 4);
    int* bsums  = (int*)alloc((size_t)SCAN_NB * 4);
    int* boffs  = (int*)alloc((size_t)SCAN_NB * 4);
    (void)in_sizes; (void)n_in; (void)out_size; (void)ws_size;

    // ---- zero what we accumulate into ----
    hipMemsetAsync(deg, 0, (size_t)N_NODES * 4, stream);

    // ---- fp16 conversions ----
    k_f2h<<<(N_NODES * NODE_DIM / 4 + 255) / 256, 256, 0, stream>>>(x, xb, N_NODES * NODE_DIM / 4);
    k_f2h<<<(HIDDEN * NODE_DIM / 4 + 255) / 256, 256, 0, stream>>>(node_w, nwb, HIDDEN * NODE_DIM / 4);
    k_f2h<<<(N_LAYERS * HIDDEN * HIDDEN / 4 + 255) / 256, 256, 0, stream>>>(gw1, w1b, N_LAYERS * HIDDEN * HIDDEN / 4);
    k_f2h<<<(N_LAYERS * HIDDEN * HIDDEN / 4 + 255) / 256, 256, 0, stream>>>(gw2, w2b, N_LAYERS * HIDDEN * HIDDEN / 4);

    // ---- CSR build ----
    k_hist<<<(N_EDGES + 255) / 256, 256, 0, stream>>>(ei, deg);
    k_scan1<<<SCAN_NB, SCAN_BLK, 0, stream>>>(deg, rowptr, bsums);
    k_scan2<<<1, 128, 0, stream>>>(bsums, boffs, rowptr);
    k_scan3<<<SCAN_NB, SCAN_BLK, 0, stream>>>(rowptr, boffs, cursor);
    k_scatter<<<(N_EDGES + 255) / 256, 256, 0, stream>>>(ei, cursor, col);

    // ---- segment bounds ----
    k_bounds<<<(N_NODES + 255) / 256, 256, 0, stream>>>(batch, starts);

    // ---- node projection ----
    const int NSLAB = (N_NODES + 255) / 256;   // 391
    k_gemm<NODE_DIM><<<256, 512, 0, stream>>>(xb, nwb, node_b, hb, N_NODES, NSLAB);

    // ---- GIN layers ----
    for (int l = 0; l < N_LAYERS; ++l) {
        k_agg<<<(N_NODES + 3) / 4, 256, 0, stream>>>(hb, rowptr, col, eps, l, zb);
        k_gemm<HIDDEN><<<256, 512, 0, stream>>>(zb, w1b + (size_t)l * HIDDEN * HIDDEN,
                                                gb1 + (size_t)l * HIDDEN, tb, N_NODES, NSLAB);
        k_gemm<HIDDEN><<<256, 512, 0, stream>>>(tb, w2b + (size_t)l * HIDDEN * HIDDEN,
                                                gb2 + (size_t)l * HIDDEN, hb, N_NODES, NSLAB);
    }

    // ---- pooling + head ----
    dim3 pgrid(N_GRAPHS, POOL_CHUNKS);
    k_pool<<<pgrid, 256, 0, stream>>>(hb, starts, part);
    k_head<<<N_GRAPHS, 256, 0, stream>>>(part, starts, ow1, ob1, ow2, ob2, out);
}

// Round 11
// 694.076 us; speedup vs baseline: 2.5500x; 1.1510x over previous
//
#include <hip/hip_runtime.h>
#include <stdint.h>

#define N_NODES   100000
#define N_EDGES   800000
#define NODE_DIM  128
#define HIDDEN    256
#define OUT_DIM   512
#define N_LAYERS  4
#define N_GRAPHS  64
#define POOL_CHUNKS 8
#define SCAN_BLK  1024
#define SCAN_NB   ((N_NODES + SCAN_BLK - 1) / SCAN_BLK)   // 98

typedef _Float16 f16;
typedef __attribute__((ext_vector_type(8))) _Float16 f16x8;
typedef __attribute__((ext_vector_type(4))) _Float16 f16x4;
typedef __attribute__((ext_vector_type(4))) float    f32x4;

// ---------------- fp32 -> fp16 conversion (vectorized) ----------------
__global__ void k_f2h(const float* __restrict__ in, f16* __restrict__ out, int n4) {
    int i = blockIdx.x * 256 + threadIdx.x;
    if (i < n4) {
        f32x4 v = *(const f32x4*)(in + (size_t)i * 4);
        f16x4 o;
        o[0] = (f16)v[0]; o[1] = (f16)v[1]; o[2] = (f16)v[2]; o[3] = (f16)v[3];
        *(f16x4*)(out + (size_t)i * 4) = o;
    }
}

// ---------------- CSR build: histogram over dst ----------------
__global__ void k_hist(const int* __restrict__ ei, int* __restrict__ deg) {
    int e = blockIdx.x * 256 + threadIdx.x;
    if (e < N_EDGES) atomicAdd(&deg[ei[N_EDGES + e]], 1);
}

// ---------------- CSR build: 3-phase device-wide exclusive scan ----------------
__global__ __launch_bounds__(1024) void k_scan1(const int* __restrict__ deg,
                                                int* __restrict__ rowptr,
                                                int* __restrict__ bsums) {
    __shared__ int tmp[SCAN_BLK];
    int tid = threadIdx.x;
    int i = blockIdx.x * SCAN_BLK + tid;
    int v = (i < N_NODES) ? deg[i] : 0;
    tmp[tid] = v;
    __syncthreads();
    for (int off = 1; off < SCAN_BLK; off <<= 1) {
        int t = (tid >= off) ? tmp[tid - off] : 0;
        __syncthreads();
        tmp[tid] += t;
        __syncthreads();
    }
    if (i < N_NODES) rowptr[i] = tmp[tid] - v;        // local exclusive prefix
    if (tid == SCAN_BLK - 1) bsums[blockIdx.x] = tmp[tid];
}

__global__ __launch_bounds__(128) void k_scan2(const int* __restrict__ bsums,
                                               int* __restrict__ boffs,
                                               int* __restrict__ rowptr) {
    __shared__ int tmp[128];
    int tid = threadIdx.x;
    int v = (tid < SCAN_NB) ? bsums[tid] : 0;
    tmp[tid] = v;
    __syncthreads();
    for (int off = 1; off < 128; off <<= 1) {
        int t = (tid >= off) ? tmp[tid - off] : 0;
        __syncthreads();
        tmp[tid] += t;
        __syncthreads();
    }
    if (tid < SCAN_NB) boffs[tid] = tmp[tid] - v;     // exclusive block offset
    if (tid == 127) rowptr[N_NODES] = tmp[127];       // total = N_EDGES
}

__global__ __launch_bounds__(1024) void k_scan3(int* __restrict__ rowptr,
                                                const int* __restrict__ boffs,
                                                int* __restrict__ cursor) {
    int i = blockIdx.x * SCAN_BLK + threadIdx.x;
    if (i < N_NODES) {
        int r = rowptr[i] + boffs[blockIdx.x];
        rowptr[i] = r;
        cursor[i] = r;
    }
}

// ---------------- CSR build: scatter src into col ----------------
__global__ void k_scatter(const int* __restrict__ ei, int* __restrict__ cursor,
                          int* __restrict__ col) {
    int e = blockIdx.x * 256 + threadIdx.x;
    if (e < N_EDGES) {
        int d = ei[N_EDGES + e];
        int p = atomicAdd(&cursor[d], 1);
        col[p] = ei[e];
    }
}

// ---------------- aggregation: z = (1+eps)*h + sum_{s in N(v)} h[s], fp16 out ----------------
// 4-deep software-pipelined gather: 4 independent 512B row-gathers in flight per wave
// (vs 1 before) -> 4x memory-level parallelism for the latency-bound random gather.
__global__ __launch_bounds__(256) void k_agg(const f16* __restrict__ h,
                                             const int* __restrict__ rowptr,
                                             const int* __restrict__ col,
                                             const float* __restrict__ eps, int layer,
                                             f16* __restrict__ z) {
    int node = blockIdx.x * 4 + (threadIdx.x >> 6);
    if (node >= N_NODES) return;
    int lane = threadIdx.x & 63;
    int c0 = lane * 4;                         // 64 lanes x 4 ch = 256
    float e1 = 1.0f + eps[layer];
    f16x4 hv = *(const f16x4*)(h + (size_t)node * HIDDEN + c0);
    float a0 = e1 * (float)hv[0], a1 = e1 * (float)hv[1];
    float a2 = e1 * (float)hv[2], a3 = e1 * (float)hv[3];
    int jb = rowptr[node], je = rowptr[node + 1];
    int j = jb;
    for (; j + 4 <= je; j += 4) {
        int s0 = col[j], s1 = col[j + 1], s2 = col[j + 2], s3 = col[j + 3];
        f16x4 v0 = *(const f16x4*)(h + (size_t)s0 * HIDDEN + c0);
        f16x4 v1 = *(const f16x4*)(h + (size_t)s1 * HIDDEN + c0);
        f16x4 v2 = *(const f16x4*)(h + (size_t)s2 * HIDDEN + c0);
        f16x4 v3 = *(const f16x4*)(h + (size_t)s3 * HIDDEN + c0);
        a0 += (float)v0[0] + (float)v1[0] + (float)v2[0] + (float)v3[0];
        a1 += (float)v0[1] + (float)v1[1] + (float)v2[1] + (float)v3[1];
        a2 += (float)v0[2] + (float)v1[2] + (float)v2[2] + (float)v3[2];
        a3 += (float)v0[3] + (float)v1[3] + (float)v2[3] + (float)v3[3];
    }
    for (; j < je; ++j) {
        int s = col[j];
        f16x4 v = *(const f16x4*)(h + (size_t)s * HIDDEN + c0);
        a0 += (float)v[0]; a1 += (float)v[1]; a2 += (float)v[2]; a3 += (float)v[3];
    }
    f16x4 o;
    o[0] = (f16)a0; o[1] = (f16)a1; o[2] = (f16)a2; o[3] = (f16)a3;
    *(f16x4*)(z + (size_t)node * HIDDEN + c0) = o;
}

// ---------------- B-resident GEMM: C[M][256] = relu(A[M][K]@B[256][K]^T + bias) ----------------
// 512 threads (8 waves), B entirely in LDS (K/64 panels of [256][64], XOR-swizzled,
// staged once via global_load_lds). Barrier-FREE persistent slab loop.
template<int K>
__global__ __launch_bounds__(512) void k_gemm(const f16* __restrict__ A,
                                              const f16* __restrict__ B,
                                              const float* __restrict__ bias,
                                              f16* __restrict__ C, int M, int nslab) {
    constexpr int NPANEL = K >> 6;           // 2 (K=128) or 4 (K=256)
    constexpr int NKS    = K >> 5;           // 4 or 8 K-steps of 32
    __shared__ f16 Bs[NPANEL * 256 * 64];    // 64 or 128 KB
    const int tid = threadIdx.x, wid = tid >> 6, lane = tid & 63;
    const int klo = lane >> 4;               // k-group 0..3
    const int l15 = lane & 15;

    // ---- stage all of B once (swizzled via pre-swizzled global source) ----
#pragma unroll
    for (int p = 0; p < NPANEL; ++p) {
#pragma unroll
        for (int r = 0; r < 4; ++r) {
            int chunk = (r << 9) + tid;                  // 0..2047 within panel
            int brow = chunk >> 3, c8 = chunk & 7;
            int sc8  = c8 ^ (brow & 7);
            const f16* src = B + (size_t)brow * K + (p << 6) + sc8 * 8;
            f16* dst = Bs + (p << 14) + (size_t)((r << 9) + (wid << 6)) * 8;
            __builtin_amdgcn_global_load_lds((const __attribute__((address_space(1))) void*)src,
                                             (__attribute__((address_space(3))) void*)dst, 16, 0, 0);
        }
    }
    __syncthreads();   // ONLY barrier in the kernel

    // ---- persistent loop over 256-row slabs; wave owns rows [r0, r0+32) ----
    for (int slab = blockIdx.x; slab < nslab; slab += gridDim.x) {
        const int r0 = slab * 256 + wid * 32;
        // prefetch all A fragments for 32 rows x K
        f16x8 a[2][NKS];
#pragma unroll
        for (int m = 0; m < 2; ++m) {
            int gr = r0 + m * 16 + l15; if (gr >= M) gr = M - 1;
            const f16* arow = A + (size_t)gr * K + (klo << 3);
#pragma unroll
            for (int ks = 0; ks < NKS; ++ks)
                a[m][ks] = *(const f16x8*)(arow + (ks << 5));
        }
        f32x4 acc[2][16] = {};
#pragma unroll
        for (int ks = 0; ks < NKS; ++ks) {
            const int kk = ((ks & 1) << 2) | klo;
            const f16* pb = Bs + ((ks >> 1) << 14);
#pragma unroll
            for (int n = 0; n < 16; ++n) {
                int rb = (n << 4) + l15;
                f16x8 bf = *(const f16x8*)(pb + rb * 64 + ((kk ^ (rb & 7)) << 3));
                acc[0][n] = __builtin_amdgcn_mfma_f32_16x16x32_f16(a[0][ks], bf, acc[0][n], 0, 0, 0);
                acc[1][n] = __builtin_amdgcn_mfma_f32_16x16x32_f16(a[1][ks], bf, acc[1][n], 0, 0, 0);
            }
        }
        // epilogue: bias + relu + fp16 store. D: col=lane&15, row=(lane>>4)*4+j
#pragma unroll
        for (int n = 0; n < 16; ++n) {
            int gc = (n << 4) + l15;
            float bv = bias[gc];
#pragma unroll
            for (int m = 0; m < 2; ++m) {
                int gr0 = r0 + (m << 4) + (klo << 2);
#pragma unroll
                for (int j = 0; j < 4; ++j) {
                    int gr = gr0 + j;
                    if (gr < M) {
                        float v = fmaxf(acc[m][n][j] + bv, 0.0f);
                        C[(size_t)gr * HIDDEN + gc] = (f16)v;
                    }
                }
            }
        }
    }
}

// ---------------- segment starts from sorted batch (atomic-free) ----------------
__global__ void k_bounds(const int* __restrict__ batch, int* __restrict__ starts) {
    int i = blockIdx.x * 256 + threadIdx.x;
    if (i >= N_NODES) return;
    int g  = batch[i];
    int gp = (i == 0) ? -1 : batch[i - 1];
    for (int q = gp + 1; q <= g; ++q) starts[q] = i;
    if (i == N_NODES - 1) {
        for (int q = g + 1; q <= N_GRAPHS; ++q) starts[q] = N_NODES;
    }
}

// ---------------- pooled partial sums (atomic-free; batch sorted & contiguous) ----------------
__global__ __launch_bounds__(256) void k_pool(const f16* __restrict__ h,
                                              const int* __restrict__ starts,
                                              float* __restrict__ part) {
    int g = blockIdx.x, ch = blockIdx.y, c = threadIdx.x;
    int s = starts[g], e = starts[g + 1];
    int len = e - s;
    int per = (len + POOL_CHUNKS - 1) / POOL_CHUNKS;
    int lo = s + ch * per;
    int hi = lo + per; if (hi > e) hi = e;
    float acc = 0.0f;
    for (int n = lo; n < hi; ++n) acc += (float)h[(size_t)n * HIDDEN + c];
    part[((size_t)g * POOL_CHUNKS + ch) * HIDDEN + c] = acc;
}

// ---------------- head MLP (fp32, tiny) ----------------
__global__ __launch_bounds__(256) void k_head(const float* __restrict__ part,
                                              const int* __restrict__ starts,
                                              const float* __restrict__ w1,
                                              const float* __restrict__ b1,
                                              const float* __restrict__ w2,
                                              const float* __restrict__ b2,
                                              float* __restrict__ out) {
    __shared__ float hg[HIDDEN];
    __shared__ float t[HIDDEN];
    int g = blockIdx.x, tid = threadIdx.x;
    int cnti = starts[g + 1] - starts[g];
    float cnt = (float)(cnti > 1 ? cnti : 1);
    float s = 0.0f;
#pragma unroll
    for (int ch = 0; ch < POOL_CHUNKS; ++ch)
        s += part[((size_t)g * POOL_CHUNKS + ch) * HIDDEN + tid];
    hg[tid] = s / cnt;
    __syncthreads();
    float a = b1[tid];
    for (int k = 0; k < HIDDEN; ++k) a += hg[k] * w1[(size_t)tid * HIDDEN + k];
    t[tid] = fmaxf(a, 0.0f);
    __syncthreads();
    for (int j = tid; j < OUT_DIM; j += 256) {
        float o = b2[j];
        for (int k = 0; k < HIDDEN; ++k) o += t[k] * w2[(size_t)j * HIDDEN + k];
        out[(size_t)g * OUT_DIM + j] = o;
    }
}

extern "C" void kernel_launch(void* const* d_in, const int* in_sizes, int n_in,
                              void* d_out, int out_size, void* d_ws, size_t ws_size,
                              hipStream_t stream) {
    const float* x      = (const float*)d_in[0];
    const int*   ei     = (const int*)d_in[1];
    const int*   batch  = (const int*)d_in[2];
    const float* node_w = (const float*)d_in[3];
    const float* node_b = (const float*)d_in[4];
    const float* gw1    = (const float*)d_in[5];
    const float* gb1    = (const float*)d_in[6];
    const float* gw2    = (const float*)d_in[7];
    const float* gb2    = (const float*)d_in[8];
    const float* eps    = (const float*)d_in[9];
    const float* ow1    = (const float*)d_in[10];
    const float* ob1    = (const float*)d_in[11];
    const float* ow2    = (const float*)d_in[12];
    const float* ob2    = (const float*)d_in[13];
    float* out = (float*)d_out;

    // ---- workspace layout ----
    char* p = (char*)d_ws;
    auto alloc = [&](size_t bytes) {
        char* r = p;
        p += (bytes + 255) & ~(size_t)255;
        return (void*)r;
    };
    f16* hb   = (f16*)alloc((size_t)N_NODES * HIDDEN * 2);
    f16* zb   = (f16*)alloc((size_t)N_NODES * HIDDEN * 2);
    f16* tb   = (f16*)alloc((size_t)N_NODES * HIDDEN * 2);
    f16* xb   = (f16*)alloc((size_t)N_NODES * NODE_DIM * 2);
    f16* nwb  = (f16*)alloc((size_t)HIDDEN * NODE_DIM * 2);
    f16* w1b  = (f16*)alloc((size_t)N_LAYERS * HIDDEN * HIDDEN * 2);
    f16* w2b  = (f16*)alloc((size_t)N_LAYERS * HIDDEN * HIDDEN * 2);
    int* deg    = (int*)alloc((size_t)N_NODES * 4);
    int* rowptr = (int*)alloc((size_t)(N_NODES + 1) * 4);
    int* cursor = (int*)alloc((size_t)N_NODES * 4);
    int* col    = (int*)alloc((size_t)N_EDGES * 4);
    float* part = (float*)alloc((size_t)N_GRAPHS * POOL_CHUNKS * HIDDEN * 4);
    int* starts = (int*)alloc((size_t)(N_GRAPHS + 1) * 4);
    int* bsums  = (int*)alloc((size_t)SCAN_NB * 4);
    int* boffs  = (int*)alloc((size_t)SCAN_NB * 4);
    (void)in_sizes; (void)n_in; (void)out_size; (void)ws_size;

    // ---- zero what we accumulate into ----
    hipMemsetAsync(deg, 0, (size_t)N_NODES * 4, stream);

    // ---- fp16 conversions ----
    k_f2h<<<(N_NODES * NODE_DIM / 4 + 255) / 256, 256, 0, stream>>>(x, xb, N_NODES * NODE_DIM / 4);
    k_f2h<<<(HIDDEN * NODE_DIM / 4 + 255) / 256, 256, 0, stream>>>(node_w, nwb, HIDDEN * NODE_DIM / 4);
    k_f2h<<<(N_LAYERS * HIDDEN * HIDDEN / 4 + 255) / 256, 256, 0, stream>>>(gw1, w1b, N_LAYERS * HIDDEN * HIDDEN / 4);
    k_f2h<<<(N_LAYERS * HIDDEN * HIDDEN / 4 + 255) / 256, 256, 0, stream>>>(gw2, w2b, N_LAYERS * HIDDEN * HIDDEN / 4);

    // ---- CSR build ----
    k_hist<<<(N_EDGES + 255) / 256, 256, 0, stream>>>(ei, deg);
    k_scan1<<<SCAN_NB, SCAN_BLK, 0, stream>>>(deg, rowptr, bsums);
    k_scan2<<<1, 128, 0, stream>>>(bsums, boffs, rowptr);
    k_scan3<<<SCAN_NB, SCAN_BLK, 0, stream>>>(rowptr, boffs, cursor);
    k_scatter<<<(N_EDGES + 255) / 256, 256, 0, stream>>>(ei, cursor, col);

    // ---- segment bounds ----
    k_bounds<<<(N_NODES + 255) / 256, 256, 0, stream>>>(batch, starts);

    // ---- node projection ----
    const int NSLAB = (N_NODES + 255) / 256;   // 391
    k_gemm<NODE_DIM><<<256, 512, 0, stream>>>(xb, nwb, node_b, hb, N_NODES, NSLAB);

    // ---- GIN layers ----
    for (int l = 0; l < N_LAYERS; ++l) {
        k_agg<<<(N_NODES + 3) / 4, 256, 0, stream>>>(hb, rowptr, col, eps, l, zb);
        k_gemm<HIDDEN><<<256, 512, 0, stream>>>(zb, w1b + (size_t)l * HIDDEN * HIDDEN,
                                                gb1 + (size_t)l * HIDDEN, tb, N_NODES, NSLAB);
        k_gemm<HIDDEN><<<256, 512, 0, stream>>>(tb, w2b + (size_t)l * HIDDEN * HIDDEN,
                                                gb2 + (size_t)l * HIDDEN, hb, N_NODES, NSLAB);
    }

    // ---- pooling + head ----
    dim3 pgrid(N_GRAPHS, POOL_CHUNKS);
    k_pool<<<pgrid, 256, 0, stream>>>(hb, starts, part);
    k_head<<<N_GRAPHS, 256, 0, stream>>>(part, starts, ow1, ob1, ow2, ob2, out);
}